// Round 3
// baseline (367.612 us; speedup 1.0000x reference)
//
#include <hip/hip_runtime.h>
#include <hip/hip_bf16.h>

typedef __attribute__((ext_vector_type(4))) float f32x4;
typedef __attribute__((ext_vector_type(8))) short bf16x8;
typedef __attribute__((ext_vector_type(4))) short short4v;

__device__ __forceinline__ short f2bf(float f) {
  union { float f; unsigned u; } x; x.f = f;
  unsigned r = x.u + 0x7fffu + ((x.u >> 16) & 1u);
  return (short)(r >> 16);
}

__device__ __forceinline__ float fexp2(float x) {
#if __has_builtin(__builtin_amdgcn_exp2f)
  return __builtin_amdgcn_exp2f(x);
#else
  return exp2f(x);
#endif
}

// ---------------- cast f32 -> bf16 (RNE), 4 elems/thread ----------------
__global__ __launch_bounds__(256) void cast_kernel(const float* __restrict__ in,
                                                   short* __restrict__ out, int n4) {
  int i = blockIdx.x * 256 + threadIdx.x;
  if (i < n4) {
    const float4 v = reinterpret_cast<const float4*>(in)[i];
    short4v s;
    s.x = f2bf(v.x); s.y = f2bf(v.y); s.z = f2bf(v.z); s.w = f2bf(v.w);
    reinterpret_cast<short4v*>(out)[i] = s;
  }
}

// ---------------- GEMM: C[M,N] = A[M,K] * B[N,K]^T ----------------
// TV=true: write output transposed per head: Vt[(b*16+h)*128 + dh][s] (bf16)
template<typename CT, bool TV>
__global__ __launch_bounds__(256) void gemm_bt(const short* __restrict__ A,
                                               const short* __restrict__ B,
                                               CT* __restrict__ C,
                                               int M, int N, int K) {
  __shared__ short As[128][72];
  __shared__ short Bs[128][72];

  const int tid  = threadIdx.x;
  const int lane = tid & 63;
  const int w    = tid >> 6;
  const int l16  = lane & 15, g = lane >> 4;
  const int wr   = w >> 1, wc = w & 1;
  const long m0  = (long)blockIdx.y * 128;
  const long n0  = (long)blockIdx.x * 128;

  const f32x4 zero4 = {0.f, 0.f, 0.f, 0.f};
  f32x4 acc[4][4];
  #pragma unroll
  for (int a = 0; a < 4; a++)
    #pragma unroll
    for (int b2 = 0; b2 < 4; b2++) acc[a][b2] = zero4;

  const int srow0 = tid >> 3;
  const int scol  = (tid & 7) * 8;

  const int ktiles = K >> 6;
  for (int kt = 0; kt < ktiles; kt++) {
    const int k0 = kt << 6;
    __syncthreads();
    #pragma unroll
    for (int j = 0; j < 4; j++) {
      const int row = j * 32 + srow0;
      *reinterpret_cast<bf16x8*>(&As[row][scol]) =
          *reinterpret_cast<const bf16x8*>(A + (m0 + row) * K + k0 + scol);
      *reinterpret_cast<bf16x8*>(&Bs[row][scol]) =
          *reinterpret_cast<const bf16x8*>(B + (n0 + row) * K + k0 + scol);
    }
    __syncthreads();
    #pragma unroll
    for (int kk = 0; kk < 2; kk++) {
      bf16x8 af[4], bfr[4];
      #pragma unroll
      for (int f = 0; f < 4; f++)
        af[f] = *reinterpret_cast<const bf16x8*>(&As[wr * 64 + f * 16 + l16][kk * 32 + g * 8]);
      #pragma unroll
      for (int f = 0; f < 4; f++)
        bfr[f] = *reinterpret_cast<const bf16x8*>(&Bs[wc * 64 + f * 16 + l16][kk * 32 + g * 8]);
      #pragma unroll
      for (int fm = 0; fm < 4; fm++)
        #pragma unroll
        for (int fn = 0; fn < 4; fn++)
          acc[fm][fn] = __builtin_amdgcn_mfma_f32_16x16x32_bf16(af[fm], bfr[fn], acc[fm][fn], 0, 0, 0);
    }
  }

  #pragma unroll
  for (int fm = 0; fm < 4; fm++)
    #pragma unroll
    for (int fn = 0; fn < 4; fn++) {
      const long row0 = m0 + wr * 64 + fm * 16 + g * 4;
      const long col  = n0 + wc * 64 + fn * 16 + l16;
      if constexpr (TV) {
        // Vt[((b*16+h)*128 + dh)][s], b=row>>11, s=row&2047, h=col>>7, dh=col&127
        const long base = (((row0 >> 11) * 16 + (col >> 7)) * 128 + (col & 127)) * 2048 + (row0 & 2047);
        short4v pk;
        #pragma unroll
        for (int i = 0; i < 4; i++) pk[i] = f2bf(acc[fm][fn][i]);
        *reinterpret_cast<short4v*>(C + base) = pk;
      } else {
        #pragma unroll
        for (int i = 0; i < 4; i++) {
          const float v = acc[fm][fn][i];
          if constexpr (sizeof(CT) == 2) C[(row0 + i) * N + col] = (CT)f2bf(v);
          else                           C[(row0 + i) * N + col] = v;
        }
      }
    }
}

// ---------------- flash attention v3 ----------------
// QBLK=128 (32 q/wave), KVBLK=64; K double-buffered in LDS w/ async stage;
// V read direct from global in transposed layout Vt[b][h][dh][s]; exp2-domain
// online softmax with defer-max; lane-partial li.
__global__ __launch_bounds__(256) void attn_kernel(const short* __restrict__ Q,
                                                   const short* __restrict__ K,
                                                   const short* __restrict__ Vt,
                                                   short* __restrict__ Z) {
  __shared__ short Ks[2][64][136];
  __shared__ short plds[4][32][72];

  const int tid  = threadIdx.x;
  const int lane = tid & 63;
  const int w    = tid >> 6;
  const int l16  = lane & 15, g = lane >> 4;

  const int id   = blockIdx.x + (blockIdx.y << 4);
  const int half = id >> 8, r = id & 255;
  const int bx   = half ? (15 - (r >> 5)) : (r >> 5);
  const int bh   = r & 31;
  const int b    = bh >> 4, h = bh & 15;
  const int q0   = bx * 128;

  const float LOG2E  = 1.4426950408889634f;
  const float slope2 = exp2f(-0.5f * (float)(h + 1)) * LOG2E;
  const float scale2 = 0.08838834764831845f * LOG2E;
  const float CLAMP2 = 1477.3197f;   // 1024*log2e

  // Q fragments
  bf16x8 qf[2][4];
  #pragma unroll
  for (int mi = 0; mi < 2; mi++) {
    const long qoff = ((long)(b * 2048 + q0 + w * 32 + mi * 16 + l16)) * 2048 + h * 128;
    #pragma unroll
    for (int c = 0; c < 4; c++)
      qf[mi][c] = *reinterpret_cast<const bf16x8*>(Q + qoff + c * 32 + g * 8);
  }

  const f32x4 zero4 = {0.f, 0.f, 0.f, 0.f};
  f32x4 zacc[2][8];
  #pragma unroll
  for (int mi = 0; mi < 2; mi++)
    #pragma unroll
    for (int s = 0; s < 8; s++) zacc[mi][s] = zero4;
  float m2[2][4], li[2][4];
  #pragma unroll
  for (int mi = 0; mi < 2; mi++)
    #pragma unroll
    for (int i = 0; i < 4; i++) { m2[mi][i] = -3e38f; li[mi][i] = 0.f; }

  float aj[4];
  #pragma unroll
  for (int ni = 0; ni < 4; ni++) aj[ni] = slope2 * (float)(ni * 16 + l16);

  const int krow = tid >> 4, kcol = (tid & 15) * 8;
  const short* Kh = K + ((long)b * 2048) * 2048 + h * 128;
  const short* Vh = Vt + ((long)(b * 16 + h) * 128) * 2048;

  bf16x8 kreg[4];
  #pragma unroll
  for (int j = 0; j < 4; j++)
    kreg[j] = *reinterpret_cast<const bf16x8*>(Kh + (long)(j * 16 + krow) * 2048 + kcol);
  #pragma unroll
  for (int j = 0; j < 4; j++)
    *reinterpret_cast<bf16x8*>(&Ks[0][j * 16 + krow][kcol]) = kreg[j];

  const int ntiles = 2 * bx + 2;
  for (int t = 0; t < ntiles; t++) {
    const int kv0 = t * 64;
    const int cur = t & 1;
    __syncthreads();   // Ks[cur] staged for all waves

    // async: issue next K tile's global loads now, hide under softmax/PV
    if (t + 1 < ntiles) {
      const short* kb = Kh + (long)(kv0 + 64) * 2048;
      #pragma unroll
      for (int j = 0; j < 4; j++)
        kreg[j] = *reinterpret_cast<const bf16x8*>(kb + (long)(j * 16 + krow) * 2048 + kcol);
    }

    const bool active = (q0 + w * 32 + 31) >= kv0;   // wave-uniform
    f32x4 sc[2][4];
    if (active) {
      #pragma unroll
      for (int mi = 0; mi < 2; mi++)
        #pragma unroll
        for (int ni = 0; ni < 4; ni++) sc[mi][ni] = zero4;
      #pragma unroll
      for (int ni = 0; ni < 4; ni++)
        #pragma unroll
        for (int kc = 0; kc < 4; kc++) {
          const bf16x8 kf = *reinterpret_cast<const bf16x8*>(&Ks[cur][ni * 16 + l16][kc * 32 + g * 8]);
          #pragma unroll
          for (int mi = 0; mi < 2; mi++)
            sc[mi][ni] = __builtin_amdgcn_mfma_f32_16x16x32_bf16(qf[mi][kc], kf, sc[mi][ni], 0, 0, 0);
        }

      // softmax pass 1: scale/clamp/alibi/mask, row max, defer check
      float bn[4];
      #pragma unroll
      for (int ni = 0; ni < 4; ni++) bn[ni] = slope2 * (float)kv0 + aj[ni];
      float best[2][4];
      int need = 0;
      #pragma unroll
      for (int mi = 0; mi < 2; mi++)
        #pragma unroll
        for (int i = 0; i < 4; i++) {
          const int qi = q0 + w * 32 + mi * 16 + g * 4 + i;
          float bb = -3e38f;
          #pragma unroll
          for (int ni = 0; ni < 4; ni++) {
            const int j = kv0 + ni * 16 + l16;
            float v = sc[mi][ni][i] * scale2;
            v = fminf(fmaxf(v, -CLAMP2), CLAMP2) + bn[ni];
            v = (j <= qi) ? v : -3e38f;
            sc[mi][ni][i] = v;
            bb = fmaxf(bb, v);
          }
          #pragma unroll
          for (int ms = 1; ms < 16; ms <<= 1) bb = fmaxf(bb, __shfl_xor(bb, ms));
          best[mi][i] = bb;
          need |= (bb > m2[mi][i] + 10.f) ? 1 : 0;
        }
      if (__any(need)) {
        #pragma unroll
        for (int mi = 0; mi < 2; mi++)
          #pragma unroll
          for (int i = 0; i < 4; i++) {
            const float mnew = fmaxf(m2[mi][i], best[mi][i]);
            const float corr = fexp2(m2[mi][i] - mnew);
            m2[mi][i] = mnew;
            li[mi][i] *= corr;
            #pragma unroll
            for (int s = 0; s < 8; s++) zacc[mi][s][i] *= corr;
          }
      }
      // pass 2: exp2, lane-partial sum, P -> plds
      #pragma unroll
      for (int mi = 0; mi < 2; mi++)
        #pragma unroll
        for (int i = 0; i < 4; i++) {
          float psum = 0.f;
          #pragma unroll
          for (int ni = 0; ni < 4; ni++) {
            const float p = fexp2(sc[mi][ni][i] - m2[mi][i]);
            plds[w][mi * 16 + g * 4 + i][ni * 16 + l16] = f2bf(p);
            psum += p;
          }
          li[mi][i] += psum;
        }
    }

    // stage next K tile into the other buffer (waits kreg vmcnt here)
    if (t + 1 < ntiles) {
      #pragma unroll
      for (int j = 0; j < 4; j++)
        *reinterpret_cast<bf16x8*>(&Ks[cur ^ 1][j * 16 + krow][kcol]) = kreg[j];
    }

    if (active) {
      bf16x8 paf[2][2];
      #pragma unroll
      for (int mi = 0; mi < 2; mi++)
        #pragma unroll
        for (int kk = 0; kk < 2; kk++)
          paf[mi][kk] = *reinterpret_cast<const bf16x8*>(&plds[w][mi * 16 + l16][kk * 32 + g * 8]);
      #pragma unroll
      for (int s = 0; s < 8; s++) {
        const short* vrow = Vh + (long)(s * 16 + l16) * 2048 + kv0;
        const bf16x8 vf0 = *reinterpret_cast<const bf16x8*>(vrow + g * 8);
        const bf16x8 vf1 = *reinterpret_cast<const bf16x8*>(vrow + 32 + g * 8);
        #pragma unroll
        for (int mi = 0; mi < 2; mi++) {
          zacc[mi][s] = __builtin_amdgcn_mfma_f32_16x16x32_bf16(paf[mi][0], vf0, zacc[mi][s], 0, 0, 0);
          zacc[mi][s] = __builtin_amdgcn_mfma_f32_16x16x32_bf16(paf[mi][1], vf1, zacc[mi][s], 0, 0, 0);
        }
      }
    }
  }

  // reduce lane-partial li across the 16 l16 lanes, then normalize + write
  #pragma unroll
  for (int mi = 0; mi < 2; mi++)
    #pragma unroll
    for (int i = 0; i < 4; i++) {
      float s = li[mi][i];
      #pragma unroll
      for (int ms = 1; ms < 16; ms <<= 1) s += __shfl_xor(s, ms);
      li[mi][i] = s;
    }
  #pragma unroll
  for (int mi = 0; mi < 2; mi++)
    #pragma unroll
    for (int s = 0; s < 8; s++)
      #pragma unroll
      for (int i = 0; i < 4; i++) {
        const int qi = q0 + w * 32 + mi * 16 + g * 4 + i;
        const float zv = zacc[mi][s][i] / li[mi][i];
        Z[((long)(b * 2048 + qi)) * 2048 + h * 128 + s * 16 + l16] = f2bf(zv);
      }
}

// ---------------- launch ----------------
extern "C" void kernel_launch(void* const* d_in, const int* in_sizes, int n_in,
                              void* d_out, int out_size, void* d_ws, size_t ws_size,
                              hipStream_t stream) {
  const float* X  = (const float*)d_in[0];
  const float* Wq = (const float*)d_in[1];
  const float* Wk = (const float*)d_in[2];
  const float* Wv = (const float*)d_in[3];
  const float* Wo = (const float*)d_in[4];
  float* out = (float*)d_out;

  short* ws  = (short*)d_ws;
  short* Xb  = ws;
  short* Wqb = ws + 8388608;
  short* Wkb = ws + 12582912;
  short* Wvb = ws + 16777216;
  short* Wob = ws + 20971520;
  short* Qb  = ws + 25165824;
  short* Kb  = ws + 33554432;
  short* Vtb = ws + 41943040;
  short* Zb  = Xb;

  cast_kernel<<<8192, 256, 0, stream>>>(X,  Xb,  2097152);
  cast_kernel<<<4096, 256, 0, stream>>>(Wq, Wqb, 1048576);
  cast_kernel<<<4096, 256, 0, stream>>>(Wk, Wkb, 1048576);
  cast_kernel<<<4096, 256, 0, stream>>>(Wv, Wvb, 1048576);
  cast_kernel<<<4096, 256, 0, stream>>>(Wo, Wob, 1048576);

  dim3 gg(16, 32);
  gemm_bt<short, false><<<gg, 256, 0, stream>>>(Xb, Wqb, Qb,  4096, 2048, 2048);
  gemm_bt<short, false><<<gg, 256, 0, stream>>>(Xb, Wkb, Kb,  4096, 2048, 2048);
  gemm_bt<short, true ><<<gg, 256, 0, stream>>>(Xb, Wvb, Vtb, 4096, 2048, 2048);

  dim3 ga(16, 32);
  attn_kernel<<<ga, 256, 0, stream>>>(Qb, Kb, Vtb, Zb);

  gemm_bt<float, false><<<gg, 256, 0, stream>>>(Zb, Wob, out, 4096, 2048, 2048);
}

// Round 4
// 294.063 us; speedup vs baseline: 1.2501x; 1.2501x over previous
//
#include <hip/hip_runtime.h>
#include <hip/hip_bf16.h>

typedef __attribute__((ext_vector_type(4))) float f32x4;
typedef __attribute__((ext_vector_type(8))) short bf16x8;
typedef __attribute__((ext_vector_type(4))) short short4v;

__device__ __forceinline__ short f2bf(float f) {
  union { float f; unsigned u; } x; x.f = f;
  unsigned r = x.u + 0x7fffu + ((x.u >> 16) & 1u);
  return (short)(r >> 16);
}

__device__ __forceinline__ float fexp2(float x) {
#if __has_builtin(__builtin_amdgcn_exp2f)
  return __builtin_amdgcn_exp2f(x);
#else
  return exp2f(x);
#endif
}

// ---------------- cast f32 -> bf16 (RNE), 4 elems/thread ----------------
__global__ __launch_bounds__(256) void cast_kernel(const float* __restrict__ in,
                                                   short* __restrict__ out, int n4) {
  int i = blockIdx.x * 256 + threadIdx.x;
  if (i < n4) {
    const float4 v = reinterpret_cast<const float4*>(in)[i];
    short4v s;
    s.x = f2bf(v.x); s.y = f2bf(v.y); s.z = f2bf(v.z); s.w = f2bf(v.w);
    reinterpret_cast<short4v*>(out)[i] = s;
  }
}

// ---------------- GEMM: C[M,N] = A[M,K] * B[N,K]^T ----------------
// TV=true: write output transposed per head: Vt[(b*16+h)*128 + dh][s] (bf16)
template<typename CT, bool TV>
__global__ __launch_bounds__(256) void gemm_bt(const short* __restrict__ A,
                                               const short* __restrict__ B,
                                               CT* __restrict__ C,
                                               int M, int N, int K) {
  __shared__ short As[128][72];
  __shared__ short Bs[128][72];

  const int tid  = threadIdx.x;
  const int lane = tid & 63;
  const int w    = tid >> 6;
  const int l16  = lane & 15, g = lane >> 4;
  const int wr   = w >> 1, wc = w & 1;
  const long m0  = (long)blockIdx.y * 128;
  const long n0  = (long)blockIdx.x * 128;

  const f32x4 zero4 = {0.f, 0.f, 0.f, 0.f};
  f32x4 acc[4][4];
  #pragma unroll
  for (int a = 0; a < 4; a++)
    #pragma unroll
    for (int b2 = 0; b2 < 4; b2++) acc[a][b2] = zero4;

  const int srow0 = tid >> 3;
  const int scol  = (tid & 7) * 8;

  const int ktiles = K >> 6;
  for (int kt = 0; kt < ktiles; kt++) {
    const int k0 = kt << 6;
    __syncthreads();
    #pragma unroll
    for (int j = 0; j < 4; j++) {
      const int row = j * 32 + srow0;
      *reinterpret_cast<bf16x8*>(&As[row][scol]) =
          *reinterpret_cast<const bf16x8*>(A + (m0 + row) * K + k0 + scol);
      *reinterpret_cast<bf16x8*>(&Bs[row][scol]) =
          *reinterpret_cast<const bf16x8*>(B + (n0 + row) * K + k0 + scol);
    }
    __syncthreads();
    #pragma unroll
    for (int kk = 0; kk < 2; kk++) {
      bf16x8 af[4], bfr[4];
      #pragma unroll
      for (int f = 0; f < 4; f++)
        af[f] = *reinterpret_cast<const bf16x8*>(&As[wr * 64 + f * 16 + l16][kk * 32 + g * 8]);
      #pragma unroll
      for (int f = 0; f < 4; f++)
        bfr[f] = *reinterpret_cast<const bf16x8*>(&Bs[wc * 64 + f * 16 + l16][kk * 32 + g * 8]);
      #pragma unroll
      for (int fm = 0; fm < 4; fm++)
        #pragma unroll
        for (int fn = 0; fn < 4; fn++)
          acc[fm][fn] = __builtin_amdgcn_mfma_f32_16x16x32_bf16(af[fm], bfr[fn], acc[fm][fn], 0, 0, 0);
    }
  }

  #pragma unroll
  for (int fm = 0; fm < 4; fm++)
    #pragma unroll
    for (int fn = 0; fn < 4; fn++) {
      const long row0 = m0 + wr * 64 + fm * 16 + g * 4;
      const long col  = n0 + wc * 64 + fn * 16 + l16;
      if constexpr (TV) {
        const long base = (((row0 >> 11) * 16 + (col >> 7)) * 128 + (col & 127)) * 2048 + (row0 & 2047);
        short4v pk;
        #pragma unroll
        for (int i = 0; i < 4; i++) pk[i] = f2bf(acc[fm][fn][i]);
        *reinterpret_cast<short4v*>(C + base) = pk;
      } else {
        #pragma unroll
        for (int i = 0; i < 4; i++) {
          const float v = acc[fm][fn][i];
          if constexpr (sizeof(CT) == 2) C[(row0 + i) * N + col] = (CT)f2bf(v);
          else                           C[(row0 + i) * N + col] = v;
        }
      }
    }
}

// ---------------- flash attention v4 ----------------
// QBLK=64 (16 q/wave), KVBLK=64; K and V^T staged in LDS (single buffer,
// reg-prefetched next tile: T14 issue-early/write-late); exp2 softmax,
// defer-max, lane-partial li. Grid 1024, heavy-bx-first (LPT).
__global__ __launch_bounds__(256, 3) void attn_kernel(const short* __restrict__ Q,
                                                      const short* __restrict__ K,
                                                      const short* __restrict__ Vt,
                                                      short* __restrict__ Z) {
  __shared__ short Ks[64][136];
  __shared__ short Vs[128][72];
  __shared__ short plds[4][16][72];

  const int tid  = threadIdx.x;
  const int lane = tid & 63;
  const int w    = tid >> 6;
  const int l16  = lane & 15, g = lane >> 4;

  const int bh = blockIdx.x;              // 0..31 (fastest: spreads heads across XCDs)
  const int bx = 31 - (int)blockIdx.y;    // heavy blocks dispatch first (LPT)
  const int b  = bh >> 4, h = bh & 15;
  const int q0 = bx * 64;

  const float LOG2E  = 1.4426950408889634f;
  const float slope2 = exp2f(-0.5f * (float)(h + 1)) * LOG2E;
  const float scale2 = 0.08838834764831845f * LOG2E;
  const float CLAMP2 = 1477.3197f;   // 1024*log2e

  // Q fragments: wave w owns q rows [q0+16w, q0+16w+16)
  bf16x8 qf[4];
  {
    const long qoff = ((long)(b * 2048 + q0 + w * 16 + l16)) * 2048 + h * 128;
    #pragma unroll
    for (int c = 0; c < 4; c++)
      qf[c] = *reinterpret_cast<const bf16x8*>(Q + qoff + c * 32 + g * 8);
  }

  const f32x4 zero4 = {0.f, 0.f, 0.f, 0.f};
  f32x4 zacc[8];
  #pragma unroll
  for (int s = 0; s < 8; s++) zacc[s] = zero4;
  float m2[4], li[4];
  #pragma unroll
  for (int i = 0; i < 4; i++) { m2[i] = -3e38f; li[i] = 0.f; }

  float aj[4];
  #pragma unroll
  for (int ni = 0; ni < 4; ni++) aj[ni] = slope2 * (float)(ni * 16 + l16);

  const int krow = tid >> 4, kcol = (tid & 15) * 8;   // K stage: 4 rows x 256B
  const int vrow = tid >> 3, vcol = (tid & 7) * 8;    // V stage: 8 lanes cover a 128B row
  const short* Kh = K + ((long)b * 2048) * 2048 + h * 128;
  const short* Vh = Vt + ((long)(b * 16 + h) * 128) * 2048;

  bf16x8 kreg[4], vreg[4];
  #pragma unroll
  for (int j = 0; j < 4; j++)
    kreg[j] = *reinterpret_cast<const bf16x8*>(Kh + (long)(j * 16 + krow) * 2048 + kcol);
  #pragma unroll
  for (int j = 0; j < 4; j++)
    vreg[j] = *reinterpret_cast<const bf16x8*>(Vh + (long)(j * 32 + vrow) * 2048 + vcol);

  const int ntiles = bx + 1;
  for (int t = 0; t < ntiles; t++) {
    const int kv0 = t * 64;
    __syncthreads();   // all waves done reading Ks/Vs of prev tile
    #pragma unroll
    for (int j = 0; j < 4; j++)
      *reinterpret_cast<bf16x8*>(&Ks[j * 16 + krow][kcol]) = kreg[j];
    #pragma unroll
    for (int j = 0; j < 4; j++)
      *reinterpret_cast<bf16x8*>(&Vs[j * 32 + vrow][vcol]) = vreg[j];
    __syncthreads();

    // QK^T: 16 q x 64 kv per wave
    f32x4 sc[4];
    #pragma unroll
    for (int ni = 0; ni < 4; ni++) sc[ni] = zero4;
    #pragma unroll
    for (int ni = 0; ni < 4; ni++)
      #pragma unroll
      for (int kc = 0; kc < 4; kc++) {
        const bf16x8 kf = *reinterpret_cast<const bf16x8*>(&Ks[ni * 16 + l16][kc * 32 + g * 8]);
        sc[ni] = __builtin_amdgcn_mfma_f32_16x16x32_bf16(qf[kc], kf, sc[ni], 0, 0, 0);
      }

    // prefetch next tile's K/V into regs (consumed after next barrier)
    if (t + 1 < ntiles) {
      const short* kb = Kh + (long)(kv0 + 64) * 2048;
      const short* vb = Vh + kv0 + 64;
      #pragma unroll
      for (int j = 0; j < 4; j++)
        kreg[j] = *reinterpret_cast<const bf16x8*>(kb + (long)(j * 16 + krow) * 2048 + kcol);
      #pragma unroll
      for (int j = 0; j < 4; j++)
        vreg[j] = *reinterpret_cast<const bf16x8*>(vb + (long)(j * 32 + vrow) * 2048 + vcol);
    }

    // online softmax (exp2 domain, defer-max THR=10)
    const float bk = slope2 * (float)kv0;
    float best[4];
    int need = 0;
    #pragma unroll
    for (int i = 0; i < 4; i++) {
      const int qi = q0 + w * 16 + g * 4 + i;
      float bb = -3e38f;
      #pragma unroll
      for (int ni = 0; ni < 4; ni++) {
        const int j = kv0 + ni * 16 + l16;
        float v = sc[ni][i] * scale2;
        v = fminf(fmaxf(v, -CLAMP2), CLAMP2) + (bk + aj[ni]);
        v = (j <= qi) ? v : -3e38f;
        sc[ni][i] = v;
        bb = fmaxf(bb, v);
      }
      #pragma unroll
      for (int ms = 1; ms < 16; ms <<= 1) bb = fmaxf(bb, __shfl_xor(bb, ms));
      best[i] = bb;
      need |= (bb > m2[i] + 10.f) ? 1 : 0;
    }
    if (__any(need)) {
      #pragma unroll
      for (int i = 0; i < 4; i++) {
        const float mnew = fmaxf(m2[i], best[i]);
        const float corr = fexp2(m2[i] - mnew);
        m2[i] = mnew;
        li[i] *= corr;
        #pragma unroll
        for (int s = 0; s < 8; s++) zacc[s][i] *= corr;
      }
    }
    #pragma unroll
    for (int i = 0; i < 4; i++) {
      float psum = 0.f;
      #pragma unroll
      for (int ni = 0; ni < 4; ni++) {
        const float p = fexp2(sc[ni][i] - m2[i]);
        plds[w][g * 4 + i][ni * 16 + l16] = f2bf(p);
        psum += p;
      }
      li[i] += psum;
    }

    // PV from LDS
    bf16x8 paf[2];
    #pragma unroll
    for (int kk = 0; kk < 2; kk++)
      paf[kk] = *reinterpret_cast<const bf16x8*>(&plds[w][l16][kk * 32 + g * 8]);
    #pragma unroll
    for (int s = 0; s < 8; s++) {
      const bf16x8 vf0 = *reinterpret_cast<const bf16x8*>(&Vs[s * 16 + l16][g * 8]);
      const bf16x8 vf1 = *reinterpret_cast<const bf16x8*>(&Vs[s * 16 + l16][32 + g * 8]);
      zacc[s] = __builtin_amdgcn_mfma_f32_16x16x32_bf16(paf[0], vf0, zacc[s], 0, 0, 0);
      zacc[s] = __builtin_amdgcn_mfma_f32_16x16x32_bf16(paf[1], vf1, zacc[s], 0, 0, 0);
    }
  }

  // reduce lane-partial li, normalize, write Z
  #pragma unroll
  for (int i = 0; i < 4; i++) {
    float s = li[i];
    #pragma unroll
    for (int ms = 1; ms < 16; ms <<= 1) s += __shfl_xor(s, ms);
    li[i] = s;
  }
  #pragma unroll
  for (int s = 0; s < 8; s++)
    #pragma unroll
    for (int i = 0; i < 4; i++) {
      const int qi = q0 + w * 16 + g * 4 + i;
      const float zv = zacc[s][i] / li[i];
      Z[((long)(b * 2048 + qi)) * 2048 + h * 128 + s * 16 + l16] = f2bf(zv);
    }
}

// ---------------- launch ----------------
extern "C" void kernel_launch(void* const* d_in, const int* in_sizes, int n_in,
                              void* d_out, int out_size, void* d_ws, size_t ws_size,
                              hipStream_t stream) {
  const float* X  = (const float*)d_in[0];
  const float* Wq = (const float*)d_in[1];
  const float* Wk = (const float*)d_in[2];
  const float* Wv = (const float*)d_in[3];
  const float* Wo = (const float*)d_in[4];
  float* out = (float*)d_out;

  short* ws  = (short*)d_ws;
  short* Xb  = ws;
  short* Wqb = ws + 8388608;
  short* Wkb = ws + 12582912;
  short* Wvb = ws + 16777216;
  short* Wob = ws + 20971520;
  short* Qb  = ws + 25165824;
  short* Kb  = ws + 33554432;
  short* Vtb = ws + 41943040;
  short* Zb  = Xb;

  cast_kernel<<<8192, 256, 0, stream>>>(X,  Xb,  2097152);
  cast_kernel<<<4096, 256, 0, stream>>>(Wq, Wqb, 1048576);
  cast_kernel<<<4096, 256, 0, stream>>>(Wk, Wkb, 1048576);
  cast_kernel<<<4096, 256, 0, stream>>>(Wv, Wvb, 1048576);
  cast_kernel<<<4096, 256, 0, stream>>>(Wo, Wob, 1048576);

  dim3 gg(16, 32);
  gemm_bt<short, false><<<gg, 256, 0, stream>>>(Xb, Wqb, Qb,  4096, 2048, 2048);
  gemm_bt<short, false><<<gg, 256, 0, stream>>>(Xb, Wkb, Kb,  4096, 2048, 2048);
  gemm_bt<short, true ><<<gg, 256, 0, stream>>>(Xb, Wvb, Vtb, 4096, 2048, 2048);

  dim3 ga(32, 32);   // x = head (bh), y = q-slot; bx = 31 - y (heavy first)
  attn_kernel<<<ga, 256, 0, stream>>>(Qb, Kb, Vtb, Zb);

  gemm_bt<float, false><<<gg, 256, 0, stream>>>(Zb, Wob, out, 4096, 2048, 2048);
}

// Round 6
// 283.685 us; speedup vs baseline: 1.2958x; 1.0366x over previous
//
#include <hip/hip_runtime.h>
#include <hip/hip_bf16.h>

typedef __attribute__((ext_vector_type(4))) float f32x4;
typedef __attribute__((ext_vector_type(8))) short bf16x8;
typedef __attribute__((ext_vector_type(4))) short short4v;

__device__ __forceinline__ short f2bf(float f) {
  union { float f; unsigned u; } x; x.f = f;
  unsigned r = x.u + 0x7fffu + ((x.u >> 16) & 1u);
  return (short)(r >> 16);
}

__device__ __forceinline__ float fexp2(float x) {
#if __has_builtin(__builtin_amdgcn_exp2f)
  return __builtin_amdgcn_exp2f(x);
#else
  return exp2f(x);
#endif
}

#define WAITVM4() { asm volatile("s_waitcnt vmcnt(4)" ::: "memory"); __builtin_amdgcn_sched_barrier(0); }
#define BARRIER() { __builtin_amdgcn_sched_barrier(0); asm volatile("s_barrier" ::: "memory"); __builtin_amdgcn_sched_barrier(0); }
#define GLD16(g, l) __builtin_amdgcn_global_load_lds((const __attribute__((address_space(1))) void*)(g), (__attribute__((address_space(3))) void*)(l), 16, 0, 0)

// ---------------- cast f32 -> bf16 (RNE), 4 elems/thread ----------------
__global__ __launch_bounds__(256) void cast_kernel(const float* __restrict__ in,
                                                   short* __restrict__ out, int n4) {
  int i = blockIdx.x * 256 + threadIdx.x;
  if (i < n4) {
    const float4 v = reinterpret_cast<const float4*>(in)[i];
    short4v s;
    s.x = f2bf(v.x); s.y = f2bf(v.y); s.z = f2bf(v.z); s.w = f2bf(v.w);
    reinterpret_cast<short4v*>(out)[i] = s;
  }
}

// all 4 weights in one dispatch; Wq/Wk/Wv -> contiguous qkv buffer, Wo -> wo
__global__ __launch_bounds__(256) void cast_w_kernel(const float* __restrict__ w0,
                                                     const float* __restrict__ w1,
                                                     const float* __restrict__ w2,
                                                     const float* __restrict__ w3,
                                                     short* __restrict__ qkv,
                                                     short* __restrict__ wo) {
  const int y = blockIdx.y;
  const float* in = (y == 0) ? w0 : (y == 1) ? w1 : (y == 2) ? w2 : w3;
  short* out = (y < 3) ? (qkv + (long)y * 4194304) : wo;
  const int i = blockIdx.x * 256 + threadIdx.x;
  const float4 v = reinterpret_cast<const float4*>(in)[i];
  short4v s;
  s.x = f2bf(v.x); s.y = f2bf(v.y); s.z = f2bf(v.z); s.w = f2bf(v.w);
  reinterpret_cast<short4v*>(out)[i] = s;
}

// ---------------- fused QKV GEMM: 256x256 tile, BK=64, 4-phase counted-vmcnt ----------------
// C[4096, 6144] = X[4096,2048] * Wqkv[6144,2048]^T ; cols [0,2048)->Q, [2048,4096)->K,
// [4096,6144)->V written transposed per head.
// Wave (wm,wn) owns, within each staging half h (rows h*128..h*128+127):
//   A rows h*128 + wm*64 + fmL*16,  B rows h*128 + wn*32 + fnL*16
// so each phase reads EXACTLY one staged half for every wave (race-free by the
// vmcnt(4) schedule: A0^k complete by k-1.P2 wait, B0^k by k-1.P3, B1^k by k.P0,
// A1^k by k.P1 — always >= 1 barrier before first read).
__global__ __launch_bounds__(512, 2) void gemm_qkv8(const short* __restrict__ A,
                                                    const short* __restrict__ W,
                                                    short* __restrict__ Qo,
                                                    short* __restrict__ Ko,
                                                    short* __restrict__ Vt) {
  __shared__ __align__(1024) char lds[131072];   // 2 buf x (A 32KB + B 32KB)
  const int tid  = threadIdx.x;
  const int lane = tid & 63;
  const int w    = tid >> 6;            // 0..7
  const int wm   = w >> 2, wn = w & 3;  // 2M x 4N wave grid
  const int l16  = lane & 15, g = lane >> 4;
  const int K    = 2048;

  // XCD-aware swizzle (384 % 8 == 0 -> bijective)
  int id = (int)blockIdx.x;
  id = (id & 7) * 48 + (id >> 3);
  const int mb = id & 15, nb = id >> 4;        // 16 M-blocks, 24 N-blocks
  const long m0 = (long)mb * 256, n0 = (long)nb * 256;

  // staging: per-lane inverse-swizzled source column (elements)
  const int srow = lane >> 3;                                           // 0..7
  const int scol = ((((lane & 7) << 4) ^ (((lane >> 5) & 1) << 5)) >> 1);
  // ds_read: per-lane swizzled column (bytes) within a 128B row
  const int colA = (g * 16) ^ (((l16 >> 2) & 1) << 5);

  f32x4 acc[8][4];
  #pragma unroll
  for (int a = 0; a < 8; a++)
    #pragma unroll
    for (int b = 0; b < 4; b++) acc[a][b] = (f32x4){0.f, 0.f, 0.f, 0.f};

  // stage one 128-row half; 2 x GLD16 per wave (16 rows x 128B each)
  #define STAGE_HALF(mat, rbase, h, kt, buf, isB)                                   \
    {                                                                               \
      const long rowg = (rbase) + (h) * 128 + w * 16 + srow;                        \
      const short* s0_ = (mat) + rowg * K + (kt) * 64 + scol;                       \
      char* d_ = lds + (buf) * 65536 + (isB) * 32768 + ((h) * 128 + w * 16) * 128;  \
      GLD16(s0_, d_);                                                               \
      GLD16(s0_ + 8LL * K, d_ + 1024);                                              \
    }

  #define RDA(buf, h, fmL, k) (*reinterpret_cast<const bf16x8*>(                    \
      lds + (buf) * 65536 + (((h) * 128 + wm * 64 + (fmL) * 16 + l16) * 128) + (k) * 64 + colA))
  #define RDB(buf, h, fnL, k) (*reinterpret_cast<const bf16x8*>(                    \
      lds + (buf) * 65536 + 32768 + (((h) * 128 + wn * 32 + (fnL) * 16 + l16) * 128) + (k) * 64 + colA))

  // prologue: stage K-tile 0 (order A0, B0, B1, A1), wait first two halves
  STAGE_HALF(A, m0, 0, 0, 0, 0);
  STAGE_HALF(W, n0, 0, 0, 0, 1);
  STAGE_HALF(W, n0, 1, 0, 0, 1);
  STAGE_HALF(A, m0, 1, 0, 0, 0);
  WAITVM4();
  BARRIER();

  bf16x8 af[4][2], bfr[2][2];
  for (int kt = 0; kt < 32; ++kt) {
    const int cur = kt & 1, nxt = cur ^ 1;
    const int ks = (kt + 1 < 32) ? (kt + 1) : kt;   // clamped prefetch source

    // ---- P0: A-half0 x B-half0 ----
    #pragma unroll
    for (int fm = 0; fm < 4; fm++)
      #pragma unroll
      for (int k = 0; k < 2; k++) af[fm][k] = RDA(cur, 0, fm, k);
    #pragma unroll
    for (int j = 0; j < 2; j++)
      #pragma unroll
      for (int k = 0; k < 2; k++) bfr[j][k] = RDB(cur, 0, j, k);
    STAGE_HALF(A, m0, 0, ks, nxt, 0);
    WAITVM4();
    BARRIER();
    __builtin_amdgcn_s_setprio(1);
    #pragma unroll
    for (int fm = 0; fm < 4; fm++)
      #pragma unroll
      for (int j = 0; j < 2; j++)
        #pragma unroll
        for (int k = 0; k < 2; k++)
          acc[fm][j] = __builtin_amdgcn_mfma_f32_16x16x32_bf16(af[fm][k], bfr[j][k], acc[fm][j], 0, 0, 0);
    __builtin_amdgcn_s_setprio(0);
    BARRIER();

    // ---- P1: A-half0 x B-half1 ----
    #pragma unroll
    for (int j = 0; j < 2; j++)
      #pragma unroll
      for (int k = 0; k < 2; k++) bfr[j][k] = RDB(cur, 1, j, k);
    STAGE_HALF(W, n0, 0, ks, nxt, 1);
    WAITVM4();
    BARRIER();
    __builtin_amdgcn_s_setprio(1);
    #pragma unroll
    for (int fm = 0; fm < 4; fm++)
      #pragma unroll
      for (int j = 0; j < 2; j++)
        #pragma unroll
        for (int k = 0; k < 2; k++)
          acc[fm][2 + j] = __builtin_amdgcn_mfma_f32_16x16x32_bf16(af[fm][k], bfr[j][k], acc[fm][2 + j], 0, 0, 0);
    __builtin_amdgcn_s_setprio(0);
    BARRIER();

    // ---- P2: A-half1 x B-half1 (keep bfr) ----
    #pragma unroll
    for (int fm = 0; fm < 4; fm++)
      #pragma unroll
      for (int k = 0; k < 2; k++) af[fm][k] = RDA(cur, 1, fm, k);
    STAGE_HALF(W, n0, 1, ks, nxt, 1);
    WAITVM4();
    BARRIER();
    __builtin_amdgcn_s_setprio(1);
    #pragma unroll
    for (int fm = 0; fm < 4; fm++)
      #pragma unroll
      for (int j = 0; j < 2; j++)
        #pragma unroll
        for (int k = 0; k < 2; k++)
          acc[4 + fm][2 + j] = __builtin_amdgcn_mfma_f32_16x16x32_bf16(af[fm][k], bfr[j][k], acc[4 + fm][2 + j], 0, 0, 0);
    __builtin_amdgcn_s_setprio(0);
    BARRIER();

    // ---- P3: A-half1 x B-half0 ----
    #pragma unroll
    for (int j = 0; j < 2; j++)
      #pragma unroll
      for (int k = 0; k < 2; k++) bfr[j][k] = RDB(cur, 0, j, k);
    STAGE_HALF(A, m0, 1, ks, nxt, 0);
    WAITVM4();
    BARRIER();
    __builtin_amdgcn_s_setprio(1);
    #pragma unroll
    for (int fm = 0; fm < 4; fm++)
      #pragma unroll
      for (int j = 0; j < 2; j++)
        #pragma unroll
        for (int k = 0; k < 2; k++)
          acc[4 + fm][j] = __builtin_amdgcn_mfma_f32_16x16x32_bf16(af[fm][k], bfr[j][k], acc[4 + fm][j], 0, 0, 0);
    __builtin_amdgcn_s_setprio(0);
    BARRIER();
  }

  // epilogue: acc[fm][fn] -> row = m0 + (fm>>2)*128 + wm*64 + (fm&3)*16 + g*4
  //                          col = n0 + (fn>>1)*128 + wn*32 + (fn&1)*16 + l16
  const int sect = (int)(n0 >> 11);   // 0=Q, 1=K, 2=V(transposed)
  #pragma unroll
  for (int fm = 0; fm < 8; fm++)
    #pragma unroll
    for (int fn = 0; fn < 4; fn++) {
      const long row0 = m0 + (fm >> 2) * 128 + wm * 64 + (fm & 3) * 16 + g * 4;
      const long col  = n0 + (fn >> 1) * 128 + wn * 32 + (fn & 1) * 16 + l16;
      if (sect == 0) {
        #pragma unroll
        for (int i = 0; i < 4; i++) Qo[(row0 + i) * 2048 + col] = f2bf(acc[fm][fn][i]);
      } else if (sect == 1) {
        #pragma unroll
        for (int i = 0; i < 4; i++) Ko[(row0 + i) * 2048 + (col - 2048)] = f2bf(acc[fm][fn][i]);
      } else {
        const long c2 = col - 4096;
        const long base = (((row0 >> 11) * 16 + (c2 >> 7)) * 128 + (c2 & 127)) * 2048 + (row0 & 2047);
        short4v pk;
        #pragma unroll
        for (int i = 0; i < 4; i++) pk[i] = f2bf(acc[fm][fn][i]);
        *reinterpret_cast<short4v*>(Vt + base) = pk;
      }
    }
  #undef STAGE_HALF
  #undef RDA
  #undef RDB
}

// ---------------- GEMM: C[M,N] = A[M,K] * B[N,K]^T (128^2, used for out-proj) ----------------
template<typename CT, bool TV>
__global__ __launch_bounds__(256) void gemm_bt(const short* __restrict__ A,
                                               const short* __restrict__ B,
                                               CT* __restrict__ C,
                                               int M, int N, int K) {
  __shared__ short As[128][72];
  __shared__ short Bs[128][72];

  const int tid  = threadIdx.x;
  const int lane = tid & 63;
  const int w    = tid >> 6;
  const int l16  = lane & 15, g = lane >> 4;
  const int wr   = w >> 1, wc = w & 1;
  const long m0  = (long)blockIdx.y * 128;
  const long n0  = (long)blockIdx.x * 128;

  const f32x4 zero4 = {0.f, 0.f, 0.f, 0.f};
  f32x4 acc[4][4];
  #pragma unroll
  for (int a = 0; a < 4; a++)
    #pragma unroll
    for (int b2 = 0; b2 < 4; b2++) acc[a][b2] = zero4;

  const int srow0 = tid >> 3;
  const int scol  = (tid & 7) * 8;

  const int ktiles = K >> 6;
  for (int kt = 0; kt < ktiles; kt++) {
    const int k0 = kt << 6;
    __syncthreads();
    #pragma unroll
    for (int j = 0; j < 4; j++) {
      const int row = j * 32 + srow0;
      *reinterpret_cast<bf16x8*>(&As[row][scol]) =
          *reinterpret_cast<const bf16x8*>(A + (m0 + row) * K + k0 + scol);
      *reinterpret_cast<bf16x8*>(&Bs[row][scol]) =
          *reinterpret_cast<const bf16x8*>(B + (n0 + row) * K + k0 + scol);
    }
    __syncthreads();
    #pragma unroll
    for (int kk = 0; kk < 2; kk++) {
      bf16x8 af[4], bfr[4];
      #pragma unroll
      for (int f = 0; f < 4; f++)
        af[f] = *reinterpret_cast<const bf16x8*>(&As[wr * 64 + f * 16 + l16][kk * 32 + g * 8]);
      #pragma unroll
      for (int f = 0; f < 4; f++)
        bfr[f] = *reinterpret_cast<const bf16x8*>(&Bs[wc * 64 + f * 16 + l16][kk * 32 + g * 8]);
      #pragma unroll
      for (int fm = 0; fm < 4; fm++)
        #pragma unroll
        for (int fn = 0; fn < 4; fn++)
          acc[fm][fn] = __builtin_amdgcn_mfma_f32_16x16x32_bf16(af[fm], bfr[fn], acc[fm][fn], 0, 0, 0);
    }
  }

  #pragma unroll
  for (int fm = 0; fm < 4; fm++)
    #pragma unroll
    for (int fn = 0; fn < 4; fn++) {
      const long row0 = m0 + wr * 64 + fm * 16 + g * 4;
      const long col  = n0 + wc * 64 + fn * 16 + l16;
      if constexpr (TV) {
        const long base = (((row0 >> 11) * 16 + (col >> 7)) * 128 + (col & 127)) * 2048 + (row0 & 2047);
        short4v pk;
        #pragma unroll
        for (int i = 0; i < 4; i++) pk[i] = f2bf(acc[fm][fn][i]);
        *reinterpret_cast<short4v*>(C + base) = pk;
      } else {
        #pragma unroll
        for (int i = 0; i < 4; i++) {
          const float v = acc[fm][fn][i];
          if constexpr (sizeof(CT) == 2) C[(row0 + i) * N + col] = (CT)f2bf(v);
          else                           C[(row0 + i) * N + col] = v;
        }
      }
    }
}

// ---------------- flash attention v4 (unchanged) ----------------
__global__ __launch_bounds__(256, 3) void attn_kernel(const short* __restrict__ Q,
                                                      const short* __restrict__ K,
                                                      const short* __restrict__ Vt,
                                                      short* __restrict__ Z) {
  __shared__ short Ks[64][136];
  __shared__ short Vs[128][72];
  __shared__ short plds[4][16][72];

  const int tid  = threadIdx.x;
  const int lane = tid & 63;
  const int w    = tid >> 6;
  const int l16  = lane & 15, g = lane >> 4;

  const int bh = blockIdx.x;
  const int bx = 31 - (int)blockIdx.y;    // heavy blocks dispatch first (LPT)
  const int b  = bh >> 4, h = bh & 15;
  const int q0 = bx * 64;

  const float LOG2E  = 1.4426950408889634f;
  const float slope2 = exp2f(-0.5f * (float)(h + 1)) * LOG2E;
  const float scale2 = 0.08838834764831845f * LOG2E;
  const float CLAMP2 = 1477.3197f;

  bf16x8 qf[4];
  {
    const long qoff = ((long)(b * 2048 + q0 + w * 16 + l16)) * 2048 + h * 128;
    #pragma unroll
    for (int c = 0; c < 4; c++)
      qf[c] = *reinterpret_cast<const bf16x8*>(Q + qoff + c * 32 + g * 8);
  }

  const f32x4 zero4 = {0.f, 0.f, 0.f, 0.f};
  f32x4 zacc[8];
  #pragma unroll
  for (int s = 0; s < 8; s++) zacc[s] = zero4;
  float m2[4], li[4];
  #pragma unroll
  for (int i = 0; i < 4; i++) { m2[i] = -3e38f; li[i] = 0.f; }

  float aj[4];
  #pragma unroll
  for (int ni = 0; ni < 4; ni++) aj[ni] = slope2 * (float)(ni * 16 + l16);

  const int krow = tid >> 4, kcol = (tid & 15) * 8;
  const int vrow = tid >> 3, vcol = (tid & 7) * 8;
  const short* Kh = K + ((long)b * 2048) * 2048 + h * 128;
  const short* Vh = Vt + ((long)(b * 16 + h) * 128) * 2048;

  bf16x8 kreg[4], vreg[4];
  #pragma unroll
  for (int j = 0; j < 4; j++)
    kreg[j] = *reinterpret_cast<const bf16x8*>(Kh + (long)(j * 16 + krow) * 2048 + kcol);
  #pragma unroll
  for (int j = 0; j < 4; j++)
    vreg[j] = *reinterpret_cast<const bf16x8*>(Vh + (long)(j * 32 + vrow) * 2048 + vcol);

  const int ntiles = bx + 1;
  for (int t = 0; t < ntiles; t++) {
    const int kv0 = t * 64;
    __syncthreads();
    #pragma unroll
    for (int j = 0; j < 4; j++)
      *reinterpret_cast<bf16x8*>(&Ks[j * 16 + krow][kcol]) = kreg[j];
    #pragma unroll
    for (int j = 0; j < 4; j++)
      *reinterpret_cast<bf16x8*>(&Vs[j * 32 + vrow][vcol]) = vreg[j];
    __syncthreads();

    f32x4 sc[4];
    #pragma unroll
    for (int ni = 0; ni < 4; ni++) sc[ni] = zero4;
    #pragma unroll
    for (int ni = 0; ni < 4; ni++)
      #pragma unroll
      for (int kc = 0; kc < 4; kc++) {
        const bf16x8 kf = *reinterpret_cast<const bf16x8*>(&Ks[ni * 16 + l16][kc * 32 + g * 8]);
        sc[ni] = __builtin_amdgcn_mfma_f32_16x16x32_bf16(qf[kc], kf, sc[ni], 0, 0, 0);
      }

    if (t + 1 < ntiles) {
      const short* kb = Kh + (long)(kv0 + 64) * 2048;
      const short* vb = Vh + kv0 + 64;
      #pragma unroll
      for (int j = 0; j < 4; j++)
        kreg[j] = *reinterpret_cast<const bf16x8*>(kb + (long)(j * 16 + krow) * 2048 + kcol);
      #pragma unroll
      for (int j = 0; j < 4; j++)
        vreg[j] = *reinterpret_cast<const bf16x8*>(vb + (long)(j * 32 + vrow) * 2048 + vcol);
    }

    const float bk = slope2 * (float)kv0;
    float best[4];
    int need = 0;
    #pragma unroll
    for (int i = 0; i < 4; i++) {
      const int qi = q0 + w * 16 + g * 4 + i;
      float bb = -3e38f;
      #pragma unroll
      for (int ni = 0; ni < 4; ni++) {
        const int j = kv0 + ni * 16 + l16;
        float v = sc[ni][i] * scale2;
        v = fminf(fmaxf(v, -CLAMP2), CLAMP2) + (bk + aj[ni]);
        v = (j <= qi) ? v : -3e38f;
        sc[ni][i] = v;
        bb = fmaxf(bb, v);
      }
      #pragma unroll
      for (int ms = 1; ms < 16; ms <<= 1) bb = fmaxf(bb, __shfl_xor(bb, ms));
      best[i] = bb;
      need |= (bb > m2[i] + 10.f) ? 1 : 0;
    }
    if (__any(need)) {
      #pragma unroll
      for (int i = 0; i < 4; i++) {
        const float mnew = fmaxf(m2[i], best[i]);
        const float corr = fexp2(m2[i] - mnew);
        m2[i] = mnew;
        li[i] *= corr;
        #pragma unroll
        for (int s = 0; s < 8; s++) zacc[s][i] *= corr;
      }
    }
    #pragma unroll
    for (int i = 0; i < 4; i++) {
      float psum = 0.f;
      #pragma unroll
      for (int ni = 0; ni < 4; ni++) {
        const float p = fexp2(sc[ni][i] - m2[i]);
        plds[w][g * 4 + i][ni * 16 + l16] = f2bf(p);
        psum += p;
      }
      li[i] += psum;
    }

    bf16x8 paf[2];
    #pragma unroll
    for (int kk = 0; kk < 2; kk++)
      paf[kk] = *reinterpret_cast<const bf16x8*>(&plds[w][l16][kk * 32 + g * 8]);
    #pragma unroll
    for (int s = 0; s < 8; s++) {
      const bf16x8 vf0 = *reinterpret_cast<const bf16x8*>(&Vs[s * 16 + l16][g * 8]);
      const bf16x8 vf1 = *reinterpret_cast<const bf16x8*>(&Vs[s * 16 + l16][32 + g * 8]);
      zacc[s] = __builtin_amdgcn_mfma_f32_16x16x32_bf16(paf[0], vf0, zacc[s], 0, 0, 0);
      zacc[s] = __builtin_amdgcn_mfma_f32_16x16x32_bf16(paf[1], vf1, zacc[s], 0, 0, 0);
    }
  }

  #pragma unroll
  for (int i = 0; i < 4; i++) {
    float s = li[i];
    #pragma unroll
    for (int ms = 1; ms < 16; ms <<= 1) s += __shfl_xor(s, ms);
    li[i] = s;
  }
  #pragma unroll
  for (int s = 0; s < 8; s++)
    #pragma unroll
    for (int i = 0; i < 4; i++) {
      const int qi = q0 + w * 16 + g * 4 + i;
      const float zv = zacc[s][i] / li[i];
      Z[((long)(b * 2048 + qi)) * 2048 + h * 128 + s * 16 + l16] = f2bf(zv);
    }
}

// ---------------- launch ----------------
extern "C" void kernel_launch(void* const* d_in, const int* in_sizes, int n_in,
                              void* d_out, int out_size, void* d_ws, size_t ws_size,
                              hipStream_t stream) {
  const float* X  = (const float*)d_in[0];
  const float* Wq = (const float*)d_in[1];
  const float* Wk = (const float*)d_in[2];
  const float* Wv = (const float*)d_in[3];
  const float* Wo = (const float*)d_in[4];
  float* out = (float*)d_out;

  short* ws    = (short*)d_ws;
  short* Xb    = ws;                     // 8,388,608
  short* Wqkvb = ws + 8388608;           // 12,582,912 (Wq|Wk|Wv rows)
  short* Wob   = ws + 20971520;          // 4,194,304
  short* Qb    = ws + 25165824;          // 8,388,608
  short* Kb    = ws + 33554432;          // 8,388,608
  short* Vtb   = ws + 41943040;          // 8,388,608
  short* Zb    = Xb;

  cast_kernel<<<8192, 256, 0, stream>>>(X, Xb, 2097152);
  dim3 gw(4096, 4);
  cast_w_kernel<<<gw, 256, 0, stream>>>(Wq, Wk, Wv, Wo, Wqkvb, Wob);

  gemm_qkv8<<<384, 512, 0, stream>>>(Xb, Wqkvb, Qb, Kb, Vtb);

  dim3 ga(32, 32);
  attn_kernel<<<ga, 256, 0, stream>>>(Qb, Kb, Vtb, Zb);

  dim3 gg(16, 32);
  gemm_bt<float, false><<<gg, 256, 0, stream>>>(Zb, Wob, out, 4096, 2048, 2048);
}

// Round 7
// 268.195 us; speedup vs baseline: 1.3707x; 1.0578x over previous
//
#include <hip/hip_runtime.h>
#include <hip/hip_bf16.h>

typedef __attribute__((ext_vector_type(4))) float f32x4;
typedef __attribute__((ext_vector_type(8))) short bf16x8;
typedef __attribute__((ext_vector_type(4))) short short4v;

__device__ __forceinline__ short f2bf(float f) {
  union { float f; unsigned u; } x; x.f = f;
  unsigned r = x.u + 0x7fffu + ((x.u >> 16) & 1u);
  return (short)(r >> 16);
}

__device__ __forceinline__ float fexp2(float x) {
#if __has_builtin(__builtin_amdgcn_exp2f)
  return __builtin_amdgcn_exp2f(x);
#else
  return exp2f(x);
#endif
}

#define WAITVM4() { asm volatile("s_waitcnt vmcnt(4)" ::: "memory"); __builtin_amdgcn_sched_barrier(0); }
#define BARRIER() { __builtin_amdgcn_sched_barrier(0); asm volatile("s_barrier" ::: "memory"); __builtin_amdgcn_sched_barrier(0); }
#define GLD16(g, l) __builtin_amdgcn_global_load_lds((const __attribute__((address_space(1))) void*)(g), (__attribute__((address_space(3))) void*)(l), 16, 0, 0)

// ---------------- cast f32 -> bf16 (RNE), 4 elems/thread ----------------
__global__ __launch_bounds__(256) void cast_kernel(const float* __restrict__ in,
                                                   short* __restrict__ out, int n4) {
  int i = blockIdx.x * 256 + threadIdx.x;
  if (i < n4) {
    const float4 v = reinterpret_cast<const float4*>(in)[i];
    short4v s;
    s.x = f2bf(v.x); s.y = f2bf(v.y); s.z = f2bf(v.z); s.w = f2bf(v.w);
    reinterpret_cast<short4v*>(out)[i] = s;
  }
}

// all 4 weights in one dispatch; Wq/Wk/Wv -> contiguous qkv buffer, Wo -> wo
__global__ __launch_bounds__(256) void cast_w_kernel(const float* __restrict__ w0,
                                                     const float* __restrict__ w1,
                                                     const float* __restrict__ w2,
                                                     const float* __restrict__ w3,
                                                     short* __restrict__ qkv,
                                                     short* __restrict__ wo) {
  const int y = blockIdx.y;
  const float* in = (y == 0) ? w0 : (y == 1) ? w1 : (y == 2) ? w2 : w3;
  short* out = (y < 3) ? (qkv + (long)y * 4194304) : wo;
  const int i = blockIdx.x * 256 + threadIdx.x;
  const float4 v = reinterpret_cast<const float4*>(in)[i];
  short4v s;
  s.x = f2bf(v.x); s.y = f2bf(v.y); s.z = f2bf(v.z); s.w = f2bf(v.w);
  reinterpret_cast<short4v*>(out)[i] = s;
}

// ---------------- fused QKV GEMM: 256x256 tile, BK=64, 4-phase counted-vmcnt ----------------
// C[4096, 6144] = X[4096,2048] * Wqkv[6144,2048]^T ; cols [0,2048)->Q, [2048,4096)->K,
// [4096,6144)->V written transposed per head.
// LDS swizzle (T2, both-sides per rule #21): logical [row][c] stored at byte
// c ^ ((row&7)<<4); staging keeps linear global_load_lds dest and permutes the
// per-lane global SOURCE column instead (same involution since row&7 == lane>>3
// for both staged 8-row groups). ds_read col applies the same XOR -> within each
// 16-lane group: 8 distinct 16B slots x 2 lanes = 2-way = free.
__global__ __launch_bounds__(512, 2) void gemm_qkv8(const short* __restrict__ A,
                                                    const short* __restrict__ W,
                                                    short* __restrict__ Qo,
                                                    short* __restrict__ Ko,
                                                    short* __restrict__ Vt) {
  __shared__ __align__(1024) char lds[131072];   // 2 buf x (A 32KB + B 32KB)
  const int tid  = threadIdx.x;
  const int lane = tid & 63;
  const int w    = tid >> 6;            // 0..7
  const int wm   = w >> 2, wn = w & 3;  // 2M x 4N wave grid
  const int l16  = lane & 15, g = lane >> 4;
  const int K    = 2048;

  // XCD-aware swizzle (384 % 8 == 0 -> bijective)
  int id = (int)blockIdx.x;
  id = (id & 7) * 48 + (id >> 3);
  const int mb = id & 15, nb = id >> 4;        // 16 M-blocks, 24 N-blocks
  const long m0 = (long)mb * 256, n0 = (long)nb * 256;

  // staging: per-lane inverse-swizzled source column (elements)
  const int srow = lane >> 3;                              // 0..7 (row&7 of both staged rows)
  const int scol = ((lane & 7) ^ srow) * 8;                // elements; *2 = byte col ^ (srow<<4)
  // ds_read swizzle term (bytes): row&7 == l16&7 for all fragment rows
  const int csw  = (l16 & 7) << 4;

  f32x4 acc[8][4];
  #pragma unroll
  for (int a = 0; a < 8; a++)
    #pragma unroll
    for (int b = 0; b < 4; b++) acc[a][b] = (f32x4){0.f, 0.f, 0.f, 0.f};

  // stage one 128-row half; 2 x GLD16 per wave (16 rows x 128B each)
  #define STAGE_HALF(mat, rbase, h, kt, buf, isB)                                   \
    {                                                                               \
      const long rowg = (rbase) + (h) * 128 + w * 16 + srow;                        \
      const short* s0_ = (mat) + rowg * K + (kt) * 64 + scol;                       \
      char* d_ = lds + (buf) * 65536 + (isB) * 32768 + ((h) * 128 + w * 16) * 128;  \
      GLD16(s0_, d_);                                                               \
      GLD16(s0_ + 8LL * K, d_ + 1024);                                              \
    }

  #define RDA(buf, h, fmL, k) (*reinterpret_cast<const bf16x8*>(                    \
      lds + (buf) * 65536 + (((h) * 128 + wm * 64 + (fmL) * 16 + l16) * 128) +      \
      (((k) * 64 + g * 16) ^ csw)))
  #define RDB(buf, h, fnL, k) (*reinterpret_cast<const bf16x8*>(                    \
      lds + (buf) * 65536 + 32768 + (((h) * 128 + wn * 32 + (fnL) * 16 + l16) * 128) + \
      (((k) * 64 + g * 16) ^ csw)))

  // prologue: stage K-tile 0 (order A0, B0, B1, A1), wait first two halves
  STAGE_HALF(A, m0, 0, 0, 0, 0);
  STAGE_HALF(W, n0, 0, 0, 0, 1);
  STAGE_HALF(W, n0, 1, 0, 0, 1);
  STAGE_HALF(A, m0, 1, 0, 0, 0);
  WAITVM4();
  BARRIER();

  bf16x8 af[4][2], bfr[2][2];
  for (int kt = 0; kt < 32; ++kt) {
    const int cur = kt & 1, nxt = cur ^ 1;
    const int ks = (kt + 1 < 32) ? (kt + 1) : kt;   // clamped prefetch source

    // ---- P0: A-half0 x B-half0 ----
    #pragma unroll
    for (int fm = 0; fm < 4; fm++)
      #pragma unroll
      for (int k = 0; k < 2; k++) af[fm][k] = RDA(cur, 0, fm, k);
    #pragma unroll
    for (int j = 0; j < 2; j++)
      #pragma unroll
      for (int k = 0; k < 2; k++) bfr[j][k] = RDB(cur, 0, j, k);
    STAGE_HALF(A, m0, 0, ks, nxt, 0);
    WAITVM4();
    BARRIER();
    __builtin_amdgcn_s_setprio(1);
    #pragma unroll
    for (int fm = 0; fm < 4; fm++)
      #pragma unroll
      for (int j = 0; j < 2; j++)
        #pragma unroll
        for (int k = 0; k < 2; k++)
          acc[fm][j] = __builtin_amdgcn_mfma_f32_16x16x32_bf16(af[fm][k], bfr[j][k], acc[fm][j], 0, 0, 0);
    __builtin_amdgcn_s_setprio(0);
    BARRIER();

    // ---- P1: A-half0 x B-half1 ----
    #pragma unroll
    for (int j = 0; j < 2; j++)
      #pragma unroll
      for (int k = 0; k < 2; k++) bfr[j][k] = RDB(cur, 1, j, k);
    STAGE_HALF(W, n0, 0, ks, nxt, 1);
    WAITVM4();
    BARRIER();
    __builtin_amdgcn_s_setprio(1);
    #pragma unroll
    for (int fm = 0; fm < 4; fm++)
      #pragma unroll
      for (int j = 0; j < 2; j++)
        #pragma unroll
        for (int k = 0; k < 2; k++)
          acc[fm][2 + j] = __builtin_amdgcn_mfma_f32_16x16x32_bf16(af[fm][k], bfr[j][k], acc[fm][2 + j], 0, 0, 0);
    __builtin_amdgcn_s_setprio(0);
    BARRIER();

    // ---- P2: A-half1 x B-half1 (keep bfr) ----
    #pragma unroll
    for (int fm = 0; fm < 4; fm++)
      #pragma unroll
      for (int k = 0; k < 2; k++) af[fm][k] = RDA(cur, 1, fm, k);
    STAGE_HALF(W, n0, 1, ks, nxt, 1);
    WAITVM4();
    BARRIER();
    __builtin_amdgcn_s_setprio(1);
    #pragma unroll
    for (int fm = 0; fm < 4; fm++)
      #pragma unroll
      for (int j = 0; j < 2; j++)
        #pragma unroll
        for (int k = 0; k < 2; k++)
          acc[4 + fm][2 + j] = __builtin_amdgcn_mfma_f32_16x16x32_bf16(af[fm][k], bfr[j][k], acc[4 + fm][2 + j], 0, 0, 0);
    __builtin_amdgcn_s_setprio(0);
    BARRIER();

    // ---- P3: A-half1 x B-half0 ----
    #pragma unroll
    for (int j = 0; j < 2; j++)
      #pragma unroll
      for (int k = 0; k < 2; k++) bfr[j][k] = RDB(cur, 0, j, k);
    STAGE_HALF(A, m0, 1, ks, nxt, 0);
    WAITVM4();
    BARRIER();
    __builtin_amdgcn_s_setprio(1);
    #pragma unroll
    for (int fm = 0; fm < 4; fm++)
      #pragma unroll
      for (int j = 0; j < 2; j++)
        #pragma unroll
        for (int k = 0; k < 2; k++)
          acc[4 + fm][j] = __builtin_amdgcn_mfma_f32_16x16x32_bf16(af[fm][k], bfr[j][k], acc[4 + fm][j], 0, 0, 0);
    __builtin_amdgcn_s_setprio(0);
    BARRIER();
  }

  // epilogue: acc[fm][fn] -> row = m0 + (fm>>2)*128 + wm*64 + (fm&3)*16 + g*4
  //                          col = n0 + (fn>>1)*128 + wn*32 + (fn&1)*16 + l16
  const int sect = (int)(n0 >> 11);   // 0=Q, 1=K, 2=V(transposed)
  #pragma unroll
  for (int fm = 0; fm < 8; fm++)
    #pragma unroll
    for (int fn = 0; fn < 4; fn++) {
      const long row0 = m0 + (fm >> 2) * 128 + wm * 64 + (fm & 3) * 16 + g * 4;
      const long col  = n0 + (fn >> 1) * 128 + wn * 32 + (fn & 1) * 16 + l16;
      if (sect == 0) {
        #pragma unroll
        for (int i = 0; i < 4; i++) Qo[(row0 + i) * 2048 + col] = f2bf(acc[fm][fn][i]);
      } else if (sect == 1) {
        #pragma unroll
        for (int i = 0; i < 4; i++) Ko[(row0 + i) * 2048 + (col - 2048)] = f2bf(acc[fm][fn][i]);
      } else {
        const long c2 = col - 4096;
        const long base = (((row0 >> 11) * 16 + (c2 >> 7)) * 128 + (c2 & 127)) * 2048 + (row0 & 2047);
        short4v pk;
        #pragma unroll
        for (int i = 0; i < 4; i++) pk[i] = f2bf(acc[fm][fn][i]);
        *reinterpret_cast<short4v*>(Vt + base) = pk;
      }
    }
  #undef STAGE_HALF
  #undef RDA
  #undef RDB
}

// ---------------- GEMM: C[M,N] = A[M,K] * B[N,K]^T (128^2, used for out-proj) ----------------
template<typename CT, bool TV>
__global__ __launch_bounds__(256) void gemm_bt(const short* __restrict__ A,
                                               const short* __restrict__ B,
                                               CT* __restrict__ C,
                                               int M, int N, int K) {
  __shared__ short As[128][72];
  __shared__ short Bs[128][72];

  const int tid  = threadIdx.x;
  const int lane = tid & 63;
  const int w    = tid >> 6;
  const int l16  = lane & 15, g = lane >> 4;
  const int wr   = w >> 1, wc = w & 1;
  const long m0  = (long)blockIdx.y * 128;
  const long n0  = (long)blockIdx.x * 128;

  const f32x4 zero4 = {0.f, 0.f, 0.f, 0.f};
  f32x4 acc[4][4];
  #pragma unroll
  for (int a = 0; a < 4; a++)
    #pragma unroll
    for (int b2 = 0; b2 < 4; b2++) acc[a][b2] = zero4;

  const int srow0 = tid >> 3;
  const int scol  = (tid & 7) * 8;

  const int ktiles = K >> 6;
  for (int kt = 0; kt < ktiles; kt++) {
    const int k0 = kt << 6;
    __syncthreads();
    #pragma unroll
    for (int j = 0; j < 4; j++) {
      const int row = j * 32 + srow0;
      *reinterpret_cast<bf16x8*>(&As[row][scol]) =
          *reinterpret_cast<const bf16x8*>(A + (m0 + row) * K + k0 + scol);
      *reinterpret_cast<bf16x8*>(&Bs[row][scol]) =
          *reinterpret_cast<const bf16x8*>(B + (n0 + row) * K + k0 + scol);
    }
    __syncthreads();
    #pragma unroll
    for (int kk = 0; kk < 2; kk++) {
      bf16x8 af[4], bfr[4];
      #pragma unroll
      for (int f = 0; f < 4; f++)
        af[f] = *reinterpret_cast<const bf16x8*>(&As[wr * 64 + f * 16 + l16][kk * 32 + g * 8]);
      #pragma unroll
      for (int f = 0; f < 4; f++)
        bfr[f] = *reinterpret_cast<const bf16x8*>(&Bs[wc * 64 + f * 16 + l16][kk * 32 + g * 8]);
      #pragma unroll
      for (int fm = 0; fm < 4; fm++)
        #pragma unroll
        for (int fn = 0; fn < 4; fn++)
          acc[fm][fn] = __builtin_amdgcn_mfma_f32_16x16x32_bf16(af[fm], bfr[fn], acc[fm][fn], 0, 0, 0);
    }
  }

  #pragma unroll
  for (int fm = 0; fm < 4; fm++)
    #pragma unroll
    for (int fn = 0; fn < 4; fn++) {
      const long row0 = m0 + wr * 64 + fm * 16 + g * 4;
      const long col  = n0 + wc * 64 + fn * 16 + l16;
      if constexpr (TV) {
        const long base = (((row0 >> 11) * 16 + (col >> 7)) * 128 + (col & 127)) * 2048 + (row0 & 2047);
        short4v pk;
        #pragma unroll
        for (int i = 0; i < 4; i++) pk[i] = f2bf(acc[fm][fn][i]);
        *reinterpret_cast<short4v*>(C + base) = pk;
      } else {
        #pragma unroll
        for (int i = 0; i < 4; i++) {
          const float v = acc[fm][fn][i];
          if constexpr (sizeof(CT) == 2) C[(row0 + i) * N + col] = (CT)f2bf(v);
          else                           C[(row0 + i) * N + col] = v;
        }
      }
    }
}

// ---------------- flash attention v4 (unchanged) ----------------
__global__ __launch_bounds__(256, 3) void attn_kernel(const short* __restrict__ Q,
                                                      const short* __restrict__ K,
                                                      const short* __restrict__ Vt,
                                                      short* __restrict__ Z) {
  __shared__ short Ks[64][136];
  __shared__ short Vs[128][72];
  __shared__ short plds[4][16][72];

  const int tid  = threadIdx.x;
  const int lane = tid & 63;
  const int w    = tid >> 6;
  const int l16  = lane & 15, g = lane >> 4;

  const int bh = blockIdx.x;
  const int bx = 31 - (int)blockIdx.y;    // heavy blocks dispatch first (LPT)
  const int b  = bh >> 4, h = bh & 15;
  const int q0 = bx * 64;

  const float LOG2E  = 1.4426950408889634f;
  const float slope2 = exp2f(-0.5f * (float)(h + 1)) * LOG2E;
  const float scale2 = 0.08838834764831845f * LOG2E;
  const float CLAMP2 = 1477.3197f;

  bf16x8 qf[4];
  {
    const long qoff = ((long)(b * 2048 + q0 + w * 16 + l16)) * 2048 + h * 128;
    #pragma unroll
    for (int c = 0; c < 4; c++)
      qf[c] = *reinterpret_cast<const bf16x8*>(Q + qoff + c * 32 + g * 8);
  }

  const f32x4 zero4 = {0.f, 0.f, 0.f, 0.f};
  f32x4 zacc[8];
  #pragma unroll
  for (int s = 0; s < 8; s++) zacc[s] = zero4;
  float m2[4], li[4];
  #pragma unroll
  for (int i = 0; i < 4; i++) { m2[i] = -3e38f; li[i] = 0.f; }

  float aj[4];
  #pragma unroll
  for (int ni = 0; ni < 4; ni++) aj[ni] = slope2 * (float)(ni * 16 + l16);

  const int krow = tid >> 4, kcol = (tid & 15) * 8;
  const int vrow = tid >> 3, vcol = (tid & 7) * 8;
  const short* Kh = K + ((long)b * 2048) * 2048 + h * 128;
  const short* Vh = Vt + ((long)(b * 16 + h) * 128) * 2048;

  bf16x8 kreg[4], vreg[4];
  #pragma unroll
  for (int j = 0; j < 4; j++)
    kreg[j] = *reinterpret_cast<const bf16x8*>(Kh + (long)(j * 16 + krow) * 2048 + kcol);
  #pragma unroll
  for (int j = 0; j < 4; j++)
    vreg[j] = *reinterpret_cast<const bf16x8*>(Vh + (long)(j * 32 + vrow) * 2048 + vcol);

  const int ntiles = bx + 1;
  for (int t = 0; t < ntiles; t++) {
    const int kv0 = t * 64;
    __syncthreads();
    #pragma unroll
    for (int j = 0; j < 4; j++)
      *reinterpret_cast<bf16x8*>(&Ks[j * 16 + krow][kcol]) = kreg[j];
    #pragma unroll
    for (int j = 0; j < 4; j++)
      *reinterpret_cast<bf16x8*>(&Vs[j * 32 + vrow][vcol]) = vreg[j];
    __syncthreads();

    f32x4 sc[4];
    #pragma unroll
    for (int ni = 0; ni < 4; ni++) sc[ni] = zero4;
    #pragma unroll
    for (int ni = 0; ni < 4; ni++)
      #pragma unroll
      for (int kc = 0; kc < 4; kc++) {
        const bf16x8 kf = *reinterpret_cast<const bf16x8*>(&Ks[ni * 16 + l16][kc * 32 + g * 8]);
        sc[ni] = __builtin_amdgcn_mfma_f32_16x16x32_bf16(qf[kc], kf, sc[ni], 0, 0, 0);
      }

    if (t + 1 < ntiles) {
      const short* kb = Kh + (long)(kv0 + 64) * 2048;
      const short* vb = Vh + kv0 + 64;
      #pragma unroll
      for (int j = 0; j < 4; j++)
        kreg[j] = *reinterpret_cast<const bf16x8*>(kb + (long)(j * 16 + krow) * 2048 + kcol);
      #pragma unroll
      for (int j = 0; j < 4; j++)
        vreg[j] = *reinterpret_cast<const bf16x8*>(vb + (long)(j * 32 + vrow) * 2048 + vcol);
    }

    const float bk = slope2 * (float)kv0;
    float best[4];
    int need = 0;
    #pragma unroll
    for (int i = 0; i < 4; i++) {
      const int qi = q0 + w * 16 + g * 4 + i;
      float bb = -3e38f;
      #pragma unroll
      for (int ni = 0; ni < 4; ni++) {
        const int j = kv0 + ni * 16 + l16;
        float v = sc[ni][i] * scale2;
        v = fminf(fmaxf(v, -CLAMP2), CLAMP2) + (bk + aj[ni]);
        v = (j <= qi) ? v : -3e38f;
        sc[ni][i] = v;
        bb = fmaxf(bb, v);
      }
      #pragma unroll
      for (int ms = 1; ms < 16; ms <<= 1) bb = fmaxf(bb, __shfl_xor(bb, ms));
      best[i] = bb;
      need |= (bb > m2[i] + 10.f) ? 1 : 0;
    }
    if (__any(need)) {
      #pragma unroll
      for (int i = 0; i < 4; i++) {
        const float mnew = fmaxf(m2[i], best[i]);
        const float corr = fexp2(m2[i] - mnew);
        m2[i] = mnew;
        li[i] *= corr;
        #pragma unroll
        for (int s = 0; s < 8; s++) zacc[s][i] *= corr;
      }
    }
    #pragma unroll
    for (int i = 0; i < 4; i++) {
      float psum = 0.f;
      #pragma unroll
      for (int ni = 0; ni < 4; ni++) {
        const float p = fexp2(sc[ni][i] - m2[i]);
        plds[w][g * 4 + i][ni * 16 + l16] = f2bf(p);
        psum += p;
      }
      li[i] += psum;
    }

    bf16x8 paf[2];
    #pragma unroll
    for (int kk = 0; kk < 2; kk++)
      paf[kk] = *reinterpret_cast<const bf16x8*>(&plds[w][l16][kk * 32 + g * 8]);
    #pragma unroll
    for (int s = 0; s < 8; s++) {
      const bf16x8 vf0 = *reinterpret_cast<const bf16x8*>(&Vs[s * 16 + l16][g * 8]);
      const bf16x8 vf1 = *reinterpret_cast<const bf16x8*>(&Vs[s * 16 + l16][32 + g * 8]);
      zacc[s] = __builtin_amdgcn_mfma_f32_16x16x32_bf16(paf[0], vf0, zacc[s], 0, 0, 0);
      zacc[s] = __builtin_amdgcn_mfma_f32_16x16x32_bf16(paf[1], vf1, zacc[s], 0, 0, 0);
    }
  }

  #pragma unroll
  for (int i = 0; i < 4; i++) {
    float s = li[i];
    #pragma unroll
    for (int ms = 1; ms < 16; ms <<= 1) s += __shfl_xor(s, ms);
    li[i] = s;
  }
  #pragma unroll
  for (int s = 0; s < 8; s++)
    #pragma unroll
    for (int i = 0; i < 4; i++) {
      const int qi = q0 + w * 16 + g * 4 + i;
      const float zv = zacc[s][i] / li[i];
      Z[((long)(b * 2048 + qi)) * 2048 + h * 128 + s * 16 + l16] = f2bf(zv);
    }
}

// ---------------- launch ----------------
extern "C" void kernel_launch(void* const* d_in, const int* in_sizes, int n_in,
                              void* d_out, int out_size, void* d_ws, size_t ws_size,
                              hipStream_t stream) {
  const float* X  = (const float*)d_in[0];
  const float* Wq = (const float*)d_in[1];
  const float* Wk = (const float*)d_in[2];
  const float* Wv = (const float*)d_in[3];
  const float* Wo = (const float*)d_in[4];
  float* out = (float*)d_out;

  short* ws    = (short*)d_ws;
  short* Xb    = ws;                     // 8,388,608
  short* Wqkvb = ws + 8388608;           // 12,582,912 (Wq|Wk|Wv rows)
  short* Wob   = ws + 20971520;          // 4,194,304
  short* Qb    = ws + 25165824;          // 8,388,608
  short* Kb    = ws + 33554432;          // 8,388,608
  short* Vtb   = ws + 41943040;          // 8,388,608
  short* Zb    = Xb;

  cast_kernel<<<8192, 256, 0, stream>>>(X, Xb, 2097152);
  dim3 gw(4096, 4);
  cast_w_kernel<<<gw, 256, 0, stream>>>(Wq, Wk, Wv, Wo, Wqkvb, Wob);

  gemm_qkv8<<<384, 512, 0, stream>>>(Xb, Wqkvb, Qb, Kb, Vtb);

  dim3 ga(32, 32);
  attn_kernel<<<ga, 256, 0, stream>>>(Qb, Kb, Vtb, Zb);

  dim3 gg(16, 32);
  gemm_bt<float, false><<<gg, 256, 0, stream>>>(Zb, Wob, out, 4096, 2048, 2048);
}

// Round 8
// 252.646 us; speedup vs baseline: 1.4550x; 1.0615x over previous
//
#include <hip/hip_runtime.h>
#include <hip/hip_bf16.h>

typedef __attribute__((ext_vector_type(4))) float f32x4;
typedef __attribute__((ext_vector_type(8))) short bf16x8;
typedef __attribute__((ext_vector_type(4))) short short4v;

__device__ __forceinline__ short f2bf(float f) {
  union { float f; unsigned u; } x; x.f = f;
  unsigned r = x.u + 0x7fffu + ((x.u >> 16) & 1u);
  return (short)(r >> 16);
}

__device__ __forceinline__ float fexp2(float x) {
#if __has_builtin(__builtin_amdgcn_exp2f)
  return __builtin_amdgcn_exp2f(x);
#else
  return exp2f(x);
#endif
}

#define WAITVM(n) { asm volatile("s_waitcnt vmcnt(" #n ")" ::: "memory"); __builtin_amdgcn_sched_barrier(0); }
#define BARRIER() { __builtin_amdgcn_sched_barrier(0); asm volatile("s_barrier" ::: "memory"); __builtin_amdgcn_sched_barrier(0); }
#define GLD16(g, l) __builtin_amdgcn_global_load_lds((const __attribute__((address_space(1))) void*)(g), (__attribute__((address_space(3))) void*)(l), 16, 0, 0)

// ---------------- cast f32 -> bf16 (RNE), 4 elems/thread ----------------
__global__ __launch_bounds__(256) void cast_kernel(const float* __restrict__ in,
                                                   short* __restrict__ out, int n4) {
  int i = blockIdx.x * 256 + threadIdx.x;
  if (i < n4) {
    const float4 v = reinterpret_cast<const float4*>(in)[i];
    short4v s;
    s.x = f2bf(v.x); s.y = f2bf(v.y); s.z = f2bf(v.z); s.w = f2bf(v.w);
    reinterpret_cast<short4v*>(out)[i] = s;
  }
}

// all 4 weights in one dispatch; Wq/Wk/Wv -> contiguous qkv buffer, Wo -> wo
__global__ __launch_bounds__(256) void cast_w_kernel(const float* __restrict__ w0,
                                                     const float* __restrict__ w1,
                                                     const float* __restrict__ w2,
                                                     const float* __restrict__ w3,
                                                     short* __restrict__ qkv,
                                                     short* __restrict__ wo) {
  const int y = blockIdx.y;
  const float* in = (y == 0) ? w0 : (y == 1) ? w1 : (y == 2) ? w2 : w3;
  short* out = (y < 3) ? (qkv + (long)y * 4194304) : wo;
  const int i = blockIdx.x * 256 + threadIdx.x;
  const float4 v = reinterpret_cast<const float4*>(in)[i];
  short4v s;
  s.x = f2bf(v.x); s.y = f2bf(v.y); s.z = f2bf(v.z); s.w = f2bf(v.w);
  reinterpret_cast<short4v*>(out)[i] = s;
}

// ---------------- fused QKV GEMM: 128x384 tile, BK=64, 3-phase counted-vmcnt ----------------
// C[4096,6144] = X[4096,2048] * Wqkv[6144,2048]^T, 512 blocks = EXACTLY 2 rounds of 256 CUs.
// LDS/buf = A(128x64,16KB) + B-halves H0..H2 (128x64,16KB each) = 64KB; double-buffered.
// Wave (wm,wn): A rows wm*64+fmL*16; B global frag (wn + 4*fj), fj=0..5 -> exactly 2
// frags per 128-row half (half h holds fj in {2h, 2h+1}) so each phase reads one half.
// Stage schedule: P0 -> {A,H0}^(kt+1), P1 -> H1, P2 -> H2.
// Read schedule:  P0 reads A,H0 (staged prev kt.P0), P1 reads H1, P2 reads H2.
// FIFO waits (steady state 8 outstanding at each wait): P0 vmcnt(6) retires H1^kt,
// P1 vmcnt(6) retires H2^kt, P2 vmcnt(4) retires {A,H0}^(kt+1) — every GLD retired
// one full phase + barrier before its first ds_read; 2-phase slack uniform.
// Swizzle (T2 both-sides): logical byte-col c stored at c ^ ((row&7)<<4); staging keeps
// linear GLD dest + inverse-permuted source col (row&7 == lane>>3); reads XOR the same.
__global__ __launch_bounds__(512, 2) void gemm_qkv8(const short* __restrict__ A,
                                                    const short* __restrict__ W,
                                                    short* __restrict__ Qo,
                                                    short* __restrict__ Ko,
                                                    short* __restrict__ Vt) {
  __shared__ __align__(1024) char lds[131072];   // 2 buf x 64KB
  const int tid  = threadIdx.x;
  const int lane = tid & 63;
  const int w    = tid >> 6;            // 0..7
  const int wm   = w >> 2, wn = w & 3;  // 2M x 4N wave grid (wave tile 64 x 96)
  const int l16  = lane & 15, g = lane >> 4;
  const int K    = 2048;

  // XCD chunk map (512 % 8 == 0, bijective): XCD x gets all 32 mb x nb in {2x,2x+1}
  int id = (int)blockIdx.x;
  id = (id & 7) * 64 + (id >> 3);
  const int mb = id & 31, nb = id >> 5;        // 32 M-blocks, 16 N-blocks
  const long m0 = (long)mb * 128, n0 = (long)nb * 384;

  // staging: per-lane inverse-swizzled source column (elements)
  const int srow = lane >> 3;                    // row&7 of both staged rows
  const int scol = ((lane & 7) ^ srow) * 8;
  // ds_read swizzle term (bytes): row&7 == l16&7 for all fragment rows
  const int csw  = (l16 & 7) << 4;

  f32x4 acc[4][6];
  #pragma unroll
  for (int a = 0; a < 4; a++)
    #pragma unroll
    for (int b = 0; b < 6; b++) acc[a][b] = (f32x4){0.f, 0.f, 0.f, 0.f};

  // one 128-row panel = 2 x GLD16 (each covers 64 lanes x 16B = 8 rows x 128B x ... 16 rows total)
  #define STAGE_A(kt, buf)                                                          \
    {                                                                               \
      const short* s0_ = A + (m0 + w * 16 + srow) * K + (kt) * 64 + scol;           \
      char* d_ = lds + (buf) * 65536 + (w * 16) * 128;                              \
      GLD16(s0_, d_);                                                               \
      GLD16(s0_ + 8LL * K, d_ + 1024);                                              \
    }
  #define STAGE_B(h, kt, buf)                                                       \
    {                                                                               \
      const short* s0_ = W + (n0 + (h) * 128 + w * 16 + srow) * K + (kt) * 64 + scol; \
      char* d_ = lds + (buf) * 65536 + 16384 + (h) * 16384 + (w * 16) * 128;        \
      GLD16(s0_, d_);                                                               \
      GLD16(s0_ + 8LL * K, d_ + 1024);                                              \
    }

  #define RDA(buf, fmL, k) (*reinterpret_cast<const bf16x8*>(                       \
      lds + (buf) * 65536 + ((wm * 64 + (fmL) * 16 + l16) * 128) +                  \
      ((((k) * 64 + g * 16)) ^ csw)))
  #define RDB(buf, h, j, k) (*reinterpret_cast<const bf16x8*>(                      \
      lds + (buf) * 65536 + 16384 + (h) * 16384 +                                   \
      ((wn * 16 + (j) * 64 + l16) * 128) + ((((k) * 64 + g * 16)) ^ csw)))

  // prologue: stage kt=0 {A,H0,H1,H2}; wait A,H0 complete (4 newest outstanding ok)
  STAGE_A(0, 0);
  STAGE_B(0, 0, 0);
  STAGE_B(1, 0, 0);
  STAGE_B(2, 0, 0);
  WAITVM(4);
  BARRIER();

  bf16x8 af[4][2], bfr[2][2];
  for (int kt = 0; kt < 32; ++kt) {
    const int cur = kt & 1, nxt = cur ^ 1;
    const int ks = (kt + 1 < 32) ? (kt + 1) : kt;   // clamped prefetch source

    // ---- P0: A x B-H0 (acc fj 0,1) ----
    #pragma unroll
    for (int fm = 0; fm < 4; fm++)
      #pragma unroll
      for (int k = 0; k < 2; k++) af[fm][k] = RDA(cur, fm, k);
    #pragma unroll
    for (int j = 0; j < 2; j++)
      #pragma unroll
      for (int k = 0; k < 2; k++) bfr[j][k] = RDB(cur, 0, j, k);
    STAGE_A(ks, nxt);
    STAGE_B(0, ks, nxt);
    WAITVM(6);
    BARRIER();
    __builtin_amdgcn_s_setprio(1);
    #pragma unroll
    for (int fm = 0; fm < 4; fm++)
      #pragma unroll
      for (int j = 0; j < 2; j++)
        #pragma unroll
        for (int k = 0; k < 2; k++)
          acc[fm][j] = __builtin_amdgcn_mfma_f32_16x16x32_bf16(af[fm][k], bfr[j][k], acc[fm][j], 0, 0, 0);
    __builtin_amdgcn_s_setprio(0);
    BARRIER();

    // ---- P1: A x B-H1 (acc fj 2,3) ----
    #pragma unroll
    for (int j = 0; j < 2; j++)
      #pragma unroll
      for (int k = 0; k < 2; k++) bfr[j][k] = RDB(cur, 1, j, k);
    STAGE_B(1, ks, nxt);
    WAITVM(6);
    BARRIER();
    __builtin_amdgcn_s_setprio(1);
    #pragma unroll
    for (int fm = 0; fm < 4; fm++)
      #pragma unroll
      for (int j = 0; j < 2; j++)
        #pragma unroll
        for (int k = 0; k < 2; k++)
          acc[fm][2 + j] = __builtin_amdgcn_mfma_f32_16x16x32_bf16(af[fm][k], bfr[j][k], acc[fm][2 + j], 0, 0, 0);
    __builtin_amdgcn_s_setprio(0);
    BARRIER();

    // ---- P2: A x B-H2 (acc fj 4,5) ----
    #pragma unroll
    for (int j = 0; j < 2; j++)
      #pragma unroll
      for (int k = 0; k < 2; k++) bfr[j][k] = RDB(cur, 2, j, k);
    STAGE_B(2, ks, nxt);
    WAITVM(4);
    BARRIER();
    __builtin_amdgcn_s_setprio(1);
    #pragma unroll
    for (int fm = 0; fm < 4; fm++)
      #pragma unroll
      for (int j = 0; j < 2; j++)
        #pragma unroll
        for (int k = 0; k < 2; k++)
          acc[fm][4 + j] = __builtin_amdgcn_mfma_f32_16x16x32_bf16(af[fm][k], bfr[j][k], acc[fm][4 + j], 0, 0, 0);
    __builtin_amdgcn_s_setprio(0);
    BARRIER();
  }

  // epilogue: acc[fm][fj] -> row = m0 + wm*64 + fm*16 + g*4, col = n0 + fj*64 + wn*16 + l16
  // section per fragment (384 does not divide 2048)
  #pragma unroll
  for (int fm = 0; fm < 4; fm++)
    #pragma unroll
    for (int fj = 0; fj < 6; fj++) {
      const long row0 = m0 + wm * 64 + fm * 16 + g * 4;
      const long col  = n0 + fj * 64 + wn * 16 + l16;
      if (col < 2048) {
        #pragma unroll
        for (int i = 0; i < 4; i++) Qo[(row0 + i) * 2048 + col] = f2bf(acc[fm][fj][i]);
      } else if (col < 4096) {
        #pragma unroll
        for (int i = 0; i < 4; i++) Ko[(row0 + i) * 2048 + (col - 2048)] = f2bf(acc[fm][fj][i]);
      } else {
        const long c2 = col - 4096;
        const long base = (((row0 >> 11) * 16 + (c2 >> 7)) * 128 + (c2 & 127)) * 2048 + (row0 & 2047);
        short4v pk;
        #pragma unroll
        for (int i = 0; i < 4; i++) pk[i] = f2bf(acc[fm][fj][i]);
        *reinterpret_cast<short4v*>(Vt + base) = pk;
      }
    }
  #undef STAGE_A
  #undef STAGE_B
  #undef RDA
  #undef RDB
}

// ---------------- GEMM: C[M,N] = A[M,K] * B[N,K]^T (128^2, used for out-proj) ----------------
template<typename CT, bool TV>
__global__ __launch_bounds__(256) void gemm_bt(const short* __restrict__ A,
                                               const short* __restrict__ B,
                                               CT* __restrict__ C,
                                               int M, int N, int K) {
  __shared__ short As[128][72];
  __shared__ short Bs[128][72];

  const int tid  = threadIdx.x;
  const int lane = tid & 63;
  const int w    = tid >> 6;
  const int l16  = lane & 15, g = lane >> 4;
  const int wr   = w >> 1, wc = w & 1;
  const long m0  = (long)blockIdx.y * 128;
  const long n0  = (long)blockIdx.x * 128;

  const f32x4 zero4 = {0.f, 0.f, 0.f, 0.f};
  f32x4 acc[4][4];
  #pragma unroll
  for (int a = 0; a < 4; a++)
    #pragma unroll
    for (int b2 = 0; b2 < 4; b2++) acc[a][b2] = zero4;

  const int srow0 = tid >> 3;
  const int scol  = (tid & 7) * 8;

  const int ktiles = K >> 6;
  for (int kt = 0; kt < ktiles; kt++) {
    const int k0 = kt << 6;
    __syncthreads();
    #pragma unroll
    for (int j = 0; j < 4; j++) {
      const int row = j * 32 + srow0;
      *reinterpret_cast<bf16x8*>(&As[row][scol]) =
          *reinterpret_cast<const bf16x8*>(A + (m0 + row) * K + k0 + scol);
      *reinterpret_cast<bf16x8*>(&Bs[row][scol]) =
          *reinterpret_cast<const bf16x8*>(B + (n0 + row) * K + k0 + scol);
    }
    __syncthreads();
    #pragma unroll
    for (int kk = 0; kk < 2; kk++) {
      bf16x8 af[4], bfr[4];
      #pragma unroll
      for (int f = 0; f < 4; f++)
        af[f] = *reinterpret_cast<const bf16x8*>(&As[wr * 64 + f * 16 + l16][kk * 32 + g * 8]);
      #pragma unroll
      for (int f = 0; f < 4; f++)
        bfr[f] = *reinterpret_cast<const bf16x8*>(&Bs[wc * 64 + f * 16 + l16][kk * 32 + g * 8]);
      #pragma unroll
      for (int fm = 0; fm < 4; fm++)
        #pragma unroll
        for (int fn = 0; fn < 4; fn++)
          acc[fm][fn] = __builtin_amdgcn_mfma_f32_16x16x32_bf16(af[fm], bfr[fn], acc[fm][fn], 0, 0, 0);
    }
  }

  #pragma unroll
  for (int fm = 0; fm < 4; fm++)
    #pragma unroll
    for (int fn = 0; fn < 4; fn++) {
      const long row0 = m0 + wr * 64 + fm * 16 + g * 4;
      const long col  = n0 + wc * 64 + fn * 16 + l16;
      if constexpr (TV) {
        const long base = (((row0 >> 11) * 16 + (col >> 7)) * 128 + (col & 127)) * 2048 + (row0 & 2047);
        short4v pk;
        #pragma unroll
        for (int i = 0; i < 4; i++) pk[i] = f2bf(acc[fm][fn][i]);
        *reinterpret_cast<short4v*>(C + base) = pk;
      } else {
        #pragma unroll
        for (int i = 0; i < 4; i++) {
          const float v = acc[fm][fn][i];
          if constexpr (sizeof(CT) == 2) C[(row0 + i) * N + col] = (CT)f2bf(v);
          else                           C[(row0 + i) * N + col] = v;
        }
      }
    }
}

// ---------------- flash attention v4 (unchanged) ----------------
__global__ __launch_bounds__(256, 3) void attn_kernel(const short* __restrict__ Q,
                                                      const short* __restrict__ K,
                                                      const short* __restrict__ Vt,
                                                      short* __restrict__ Z) {
  __shared__ short Ks[64][136];
  __shared__ short Vs[128][72];
  __shared__ short plds[4][16][72];

  const int tid  = threadIdx.x;
  const int lane = tid & 63;
  const int w    = tid >> 6;
  const int l16  = lane & 15, g = lane >> 4;

  const int bh = blockIdx.x;
  const int bx = 31 - (int)blockIdx.y;    // heavy blocks dispatch first (LPT)
  const int b  = bh >> 4, h = bh & 15;
  const int q0 = bx * 64;

  const float LOG2E  = 1.4426950408889634f;
  const float slope2 = exp2f(-0.5f * (float)(h + 1)) * LOG2E;
  const float scale2 = 0.08838834764831845f * LOG2E;
  const float CLAMP2 = 1477.3197f;

  bf16x8 qf[4];
  {
    const long qoff = ((long)(b * 2048 + q0 + w * 16 + l16)) * 2048 + h * 128;
    #pragma unroll
    for (int c = 0; c < 4; c++)
      qf[c] = *reinterpret_cast<const bf16x8*>(Q + qoff + c * 32 + g * 8);
  }

  const f32x4 zero4 = {0.f, 0.f, 0.f, 0.f};
  f32x4 zacc[8];
  #pragma unroll
  for (int s = 0; s < 8; s++) zacc[s] = zero4;
  float m2[4], li[4];
  #pragma unroll
  for (int i = 0; i < 4; i++) { m2[i] = -3e38f; li[i] = 0.f; }

  float aj[4];
  #pragma unroll
  for (int ni = 0; ni < 4; ni++) aj[ni] = slope2 * (float)(ni * 16 + l16);

  const int krow = tid >> 4, kcol = (tid & 15) * 8;
  const int vrow = tid >> 3, vcol = (tid & 7) * 8;
  const short* Kh = K + ((long)b * 2048) * 2048 + h * 128;
  const short* Vh = Vt + ((long)(b * 16 + h) * 128) * 2048;

  bf16x8 kreg[4], vreg[4];
  #pragma unroll
  for (int j = 0; j < 4; j++)
    kreg[j] = *reinterpret_cast<const bf16x8*>(Kh + (long)(j * 16 + krow) * 2048 + kcol);
  #pragma unroll
  for (int j = 0; j < 4; j++)
    vreg[j] = *reinterpret_cast<const bf16x8*>(Vh + (long)(j * 32 + vrow) * 2048 + vcol);

  const int ntiles = bx + 1;
  for (int t = 0; t < ntiles; t++) {
    const int kv0 = t * 64;
    __syncthreads();
    #pragma unroll
    for (int j = 0; j < 4; j++)
      *reinterpret_cast<bf16x8*>(&Ks[j * 16 + krow][kcol]) = kreg[j];
    #pragma unroll
    for (int j = 0; j < 4; j++)
      *reinterpret_cast<bf16x8*>(&Vs[j * 32 + vrow][vcol]) = vreg[j];
    __syncthreads();

    f32x4 sc[4];
    #pragma unroll
    for (int ni = 0; ni < 4; ni++) sc[ni] = zero4;
    #pragma unroll
    for (int ni = 0; ni < 4; ni++)
      #pragma unroll
      for (int kc = 0; kc < 4; kc++) {
        const bf16x8 kf = *reinterpret_cast<const bf16x8*>(&Ks[ni * 16 + l16][kc * 32 + g * 8]);
        sc[ni] = __builtin_amdgcn_mfma_f32_16x16x32_bf16(qf[kc], kf, sc[ni], 0, 0, 0);
      }

    if (t + 1 < ntiles) {
      const short* kb = Kh + (long)(kv0 + 64) * 2048;
      const short* vb = Vh + kv0 + 64;
      #pragma unroll
      for (int j = 0; j < 4; j++)
        kreg[j] = *reinterpret_cast<const bf16x8*>(kb + (long)(j * 16 + krow) * 2048 + kcol);
      #pragma unroll
      for (int j = 0; j < 4; j++)
        vreg[j] = *reinterpret_cast<const bf16x8*>(vb + (long)(j * 32 + vrow) * 2048 + vcol);
    }

    const float bk = slope2 * (float)kv0;
    float best[4];
    int need = 0;
    #pragma unroll
    for (int i = 0; i < 4; i++) {
      const int qi = q0 + w * 16 + g * 4 + i;
      float bb = -3e38f;
      #pragma unroll
      for (int ni = 0; ni < 4; ni++) {
        const int j = kv0 + ni * 16 + l16;
        float v = sc[ni][i] * scale2;
        v = fminf(fmaxf(v, -CLAMP2), CLAMP2) + (bk + aj[ni]);
        v = (j <= qi) ? v : -3e38f;
        sc[ni][i] = v;
        bb = fmaxf(bb, v);
      }
      #pragma unroll
      for (int ms = 1; ms < 16; ms <<= 1) bb = fmaxf(bb, __shfl_xor(bb, ms));
      best[i] = bb;
      need |= (bb > m2[i] + 10.f) ? 1 : 0;
    }
    if (__any(need)) {
      #pragma unroll
      for (int i = 0; i < 4; i++) {
        const float mnew = fmaxf(m2[i], best[i]);
        const float corr = fexp2(m2[i] - mnew);
        m2[i] = mnew;
        li[i] *= corr;
        #pragma unroll
        for (int s = 0; s < 8; s++) zacc[s][i] *= corr;
      }
    }
    #pragma unroll
    for (int i = 0; i < 4; i++) {
      float psum = 0.f;
      #pragma unroll
      for (int ni = 0; ni < 4; ni++) {
        const float p = fexp2(sc[ni][i] - m2[i]);
        plds[w][g * 4 + i][ni * 16 + l16] = f2bf(p);
        psum += p;
      }
      li[i] += psum;
    }

    bf16x8 paf[2];
    #pragma unroll
    for (int kk = 0; kk < 2; kk++)
      paf[kk] = *reinterpret_cast<const bf16x8*>(&plds[w][l16][kk * 32 + g * 8]);
    #pragma unroll
    for (int s = 0; s < 8; s++) {
      const bf16x8 vf0 = *reinterpret_cast<const bf16x8*>(&Vs[s * 16 + l16][g * 8]);
      const bf16x8 vf1 = *reinterpret_cast<const bf16x8*>(&Vs[s * 16 + l16][32 + g * 8]);
      zacc[s] = __builtin_amdgcn_mfma_f32_16x16x32_bf16(paf[0], vf0, zacc[s], 0, 0, 0);
      zacc[s] = __builtin_amdgcn_mfma_f32_16x16x32_bf16(paf[1], vf1, zacc[s], 0, 0, 0);
    }
  }

  #pragma unroll
  for (int i = 0; i < 4; i++) {
    float s = li[i];
    #pragma unroll
    for (int ms = 1; ms < 16; ms <<= 1) s += __shfl_xor(s, ms);
    li[i] = s;
  }
  #pragma unroll
  for (int s = 0; s < 8; s++)
    #pragma unroll
    for (int i = 0; i < 4; i++) {
      const int qi = q0 + w * 16 + g * 4 + i;
      const float zv = zacc[s][i] / li[i];
      Z[((long)(b * 2048 + qi)) * 2048 + h * 128 + s * 16 + l16] = f2bf(zv);
    }
}

// ---------------- launch ----------------
extern "C" void kernel_launch(void* const* d_in, const int* in_sizes, int n_in,
                              void* d_out, int out_size, void* d_ws, size_t ws_size,
                              hipStream_t stream) {
  const float* X  = (const float*)d_in[0];
  const float* Wq = (const float*)d_in[1];
  const float* Wk = (const float*)d_in[2];
  const float* Wv = (const float*)d_in[3];
  const float* Wo = (const float*)d_in[4];
  float* out = (float*)d_out;

  short* ws    = (short*)d_ws;
  short* Xb    = ws;                     // 8,388,608
  short* Wqkvb = ws + 8388608;           // 12,582,912 (Wq|Wk|Wv rows)
  short* Wob   = ws + 20971520;          // 4,194,304
  short* Qb    = ws + 25165824;          // 8,388,608
  short* Kb    = ws + 33554432;          // 8,388,608
  short* Vtb   = ws + 41943040;          // 8,388,608
  short* Zb    = Xb;

  cast_kernel<<<8192, 256, 0, stream>>>(X, Xb, 2097152);
  dim3 gw(4096, 4);
  cast_w_kernel<<<gw, 256, 0, stream>>>(Wq, Wk, Wv, Wo, Wqkvb, Wob);

  gemm_qkv8<<<512, 512, 0, stream>>>(Xb, Wqkvb, Qb, Kb, Vtb);

  dim3 ga(32, 32);
  attn_kernel<<<ga, 256, 0, stream>>>(Qb, Kb, Vtb, Zb);

  dim3 gg(16, 32);
  gemm_bt<float, false><<<gg, 256, 0, stream>>>(Zb, Wob, out, 4096, 2048, 2048);
}

// Round 9
// 249.049 us; speedup vs baseline: 1.4761x; 1.0144x over previous
//
#include <hip/hip_runtime.h>
#include <hip/hip_bf16.h>

typedef __attribute__((ext_vector_type(4))) float f32x4;
typedef __attribute__((ext_vector_type(8))) short bf16x8;
typedef __attribute__((ext_vector_type(4))) short short4v;

__device__ __forceinline__ short f2bf(float f) {
  union { float f; unsigned u; } x; x.f = f;
  unsigned r = x.u + 0x7fffu + ((x.u >> 16) & 1u);
  return (short)(r >> 16);
}

__device__ __forceinline__ float fexp2(float x) {
#if __has_builtin(__builtin_amdgcn_exp2f)
  return __builtin_amdgcn_exp2f(x);
#else
  return exp2f(x);
#endif
}

#define WAITVM(n) { asm volatile("s_waitcnt vmcnt(" #n ")" ::: "memory"); __builtin_amdgcn_sched_barrier(0); }
#define BARRIER() { __builtin_amdgcn_sched_barrier(0); asm volatile("s_barrier" ::: "memory"); __builtin_amdgcn_sched_barrier(0); }
#define GLD16(g, l) __builtin_amdgcn_global_load_lds((const __attribute__((address_space(1))) void*)(g), (__attribute__((address_space(3))) void*)(l), 16, 0, 0)

// Q pre-scale folded into the QKV GEMM epilogue: scale/sqrt(dh) * log2(e)
#define QSC (0.08838834764831845f * 1.4426950408889634f)

// ---------------- cast f32 -> bf16 (RNE), 4 elems/thread ----------------
__global__ __launch_bounds__(256) void cast_kernel(const float* __restrict__ in,
                                                   short* __restrict__ out, int n4) {
  int i = blockIdx.x * 256 + threadIdx.x;
  if (i < n4) {
    const float4 v = reinterpret_cast<const float4*>(in)[i];
    short4v s;
    s.x = f2bf(v.x); s.y = f2bf(v.y); s.z = f2bf(v.z); s.w = f2bf(v.w);
    reinterpret_cast<short4v*>(out)[i] = s;
  }
}

// all 4 weights in one dispatch; Wq/Wk/Wv -> contiguous qkv buffer, Wo -> wo
__global__ __launch_bounds__(256) void cast_w_kernel(const float* __restrict__ w0,
                                                     const float* __restrict__ w1,
                                                     const float* __restrict__ w2,
                                                     const float* __restrict__ w3,
                                                     short* __restrict__ qkv,
                                                     short* __restrict__ wo) {
  const int y = blockIdx.y;
  const float* in = (y == 0) ? w0 : (y == 1) ? w1 : (y == 2) ? w2 : w3;
  short* out = (y < 3) ? (qkv + (long)y * 4194304) : wo;
  const int i = blockIdx.x * 256 + threadIdx.x;
  const float4 v = reinterpret_cast<const float4*>(in)[i];
  short4v s;
  s.x = f2bf(v.x); s.y = f2bf(v.y); s.z = f2bf(v.z); s.w = f2bf(v.w);
  reinterpret_cast<short4v*>(out)[i] = s;
}

// ---------------- fused QKV GEMM: 128x384 tile, BK=64, 3-phase counted-vmcnt ----------------
// (structure unchanged from round 8 — see comments there; only Q epilogue gains *QSC)
__global__ __launch_bounds__(512, 2) void gemm_qkv8(const short* __restrict__ A,
                                                    const short* __restrict__ W,
                                                    short* __restrict__ Qo,
                                                    short* __restrict__ Ko,
                                                    short* __restrict__ Vt) {
  __shared__ __align__(1024) char lds[131072];   // 2 buf x 64KB
  const int tid  = threadIdx.x;
  const int lane = tid & 63;
  const int w    = tid >> 6;            // 0..7
  const int wm   = w >> 2, wn = w & 3;  // 2M x 4N wave grid (wave tile 64 x 96)
  const int l16  = lane & 15, g = lane >> 4;
  const int K    = 2048;

  // XCD chunk map (512 % 8 == 0, bijective)
  int id = (int)blockIdx.x;
  id = (id & 7) * 64 + (id >> 3);
  const int mb = id & 31, nb = id >> 5;        // 32 M-blocks, 16 N-blocks
  const long m0 = (long)mb * 128, n0 = (long)nb * 384;

  const int srow = lane >> 3;                    // row&7 of both staged rows
  const int scol = ((lane & 7) ^ srow) * 8;
  const int csw  = (l16 & 7) << 4;

  f32x4 acc[4][6];
  #pragma unroll
  for (int a = 0; a < 4; a++)
    #pragma unroll
    for (int b = 0; b < 6; b++) acc[a][b] = (f32x4){0.f, 0.f, 0.f, 0.f};

  #define STAGE_A(kt, buf)                                                          \
    {                                                                               \
      const short* s0_ = A + (m0 + w * 16 + srow) * K + (kt) * 64 + scol;           \
      char* d_ = lds + (buf) * 65536 + (w * 16) * 128;                              \
      GLD16(s0_, d_);                                                               \
      GLD16(s0_ + 8LL * K, d_ + 1024);                                              \
    }
  #define STAGE_B(h, kt, buf)                                                       \
    {                                                                               \
      const short* s0_ = W + (n0 + (h) * 128 + w * 16 + srow) * K + (kt) * 64 + scol; \
      char* d_ = lds + (buf) * 65536 + 16384 + (h) * 16384 + (w * 16) * 128;        \
      GLD16(s0_, d_);                                                               \
      GLD16(s0_ + 8LL * K, d_ + 1024);                                              \
    }

  #define RDA(buf, fmL, k) (*reinterpret_cast<const bf16x8*>(                       \
      lds + (buf) * 65536 + ((wm * 64 + (fmL) * 16 + l16) * 128) +                  \
      ((((k) * 64 + g * 16)) ^ csw)))
  #define RDB(buf, h, j, k) (*reinterpret_cast<const bf16x8*>(                      \
      lds + (buf) * 65536 + 16384 + (h) * 16384 +                                   \
      ((wn * 16 + (j) * 64 + l16) * 128) + ((((k) * 64 + g * 16)) ^ csw)))

  STAGE_A(0, 0);
  STAGE_B(0, 0, 0);
  STAGE_B(1, 0, 0);
  STAGE_B(2, 0, 0);
  WAITVM(4);
  BARRIER();

  bf16x8 af[4][2], bfr[2][2];
  for (int kt = 0; kt < 32; ++kt) {
    const int cur = kt & 1, nxt = cur ^ 1;
    const int ks = (kt + 1 < 32) ? (kt + 1) : kt;

    // ---- P0: A x B-H0 (acc fj 0,1) ----
    #pragma unroll
    for (int fm = 0; fm < 4; fm++)
      #pragma unroll
      for (int k = 0; k < 2; k++) af[fm][k] = RDA(cur, fm, k);
    #pragma unroll
    for (int j = 0; j < 2; j++)
      #pragma unroll
      for (int k = 0; k < 2; k++) bfr[j][k] = RDB(cur, 0, j, k);
    STAGE_A(ks, nxt);
    STAGE_B(0, ks, nxt);
    WAITVM(6);
    BARRIER();
    __builtin_amdgcn_s_setprio(1);
    #pragma unroll
    for (int fm = 0; fm < 4; fm++)
      #pragma unroll
      for (int j = 0; j < 2; j++)
        #pragma unroll
        for (int k = 0; k < 2; k++)
          acc[fm][j] = __builtin_amdgcn_mfma_f32_16x16x32_bf16(af[fm][k], bfr[j][k], acc[fm][j], 0, 0, 0);
    __builtin_amdgcn_s_setprio(0);
    BARRIER();

    // ---- P1: A x B-H1 (acc fj 2,3) ----
    #pragma unroll
    for (int j = 0; j < 2; j++)
      #pragma unroll
      for (int k = 0; k < 2; k++) bfr[j][k] = RDB(cur, 1, j, k);
    STAGE_B(1, ks, nxt);
    WAITVM(6);
    BARRIER();
    __builtin_amdgcn_s_setprio(1);
    #pragma unroll
    for (int fm = 0; fm < 4; fm++)
      #pragma unroll
      for (int j = 0; j < 2; j++)
        #pragma unroll
        for (int k = 0; k < 2; k++)
          acc[fm][2 + j] = __builtin_amdgcn_mfma_f32_16x16x32_bf16(af[fm][k], bfr[j][k], acc[fm][2 + j], 0, 0, 0);
    __builtin_amdgcn_s_setprio(0);
    BARRIER();

    // ---- P2: A x B-H2 (acc fj 4,5) ----
    #pragma unroll
    for (int j = 0; j < 2; j++)
      #pragma unroll
      for (int k = 0; k < 2; k++) bfr[j][k] = RDB(cur, 2, j, k);
    STAGE_B(2, ks, nxt);
    WAITVM(4);
    BARRIER();
    __builtin_amdgcn_s_setprio(1);
    #pragma unroll
    for (int fm = 0; fm < 4; fm++)
      #pragma unroll
      for (int j = 0; j < 2; j++)
        #pragma unroll
        for (int k = 0; k < 2; k++)
          acc[fm][4 + j] = __builtin_amdgcn_mfma_f32_16x16x32_bf16(af[fm][k], bfr[j][k], acc[fm][4 + j], 0, 0, 0);
    __builtin_amdgcn_s_setprio(0);
    BARRIER();
  }

  // epilogue: row = m0 + wm*64 + fm*16 + g*4, col = n0 + fj*64 + wn*16 + l16
  #pragma unroll
  for (int fm = 0; fm < 4; fm++)
    #pragma unroll
    for (int fj = 0; fj < 6; fj++) {
      const long row0 = m0 + wm * 64 + fm * 16 + g * 4;
      const long col  = n0 + fj * 64 + wn * 16 + l16;
      if (col < 2048) {
        #pragma unroll
        for (int i = 0; i < 4; i++) Qo[(row0 + i) * 2048 + col] = f2bf(acc[fm][fj][i] * QSC);
      } else if (col < 4096) {
        #pragma unroll
        for (int i = 0; i < 4; i++) Ko[(row0 + i) * 2048 + (col - 2048)] = f2bf(acc[fm][fj][i]);
      } else {
        const long c2 = col - 4096;
        const long base = (((row0 >> 11) * 16 + (c2 >> 7)) * 128 + (c2 & 127)) * 2048 + (row0 & 2047);
        short4v pk;
        #pragma unroll
        for (int i = 0; i < 4; i++) pk[i] = f2bf(acc[fm][fj][i]);
        *reinterpret_cast<short4v*>(Vt + base) = pk;
      }
    }
  #undef STAGE_A
  #undef STAGE_B
  #undef RDA
  #undef RDB
}

// ---------------- GEMM: C[M,N] = A[M,K] * B[N,K]^T (128^2, used for out-proj) ----------------
template<typename CT, bool TV>
__global__ __launch_bounds__(256) void gemm_bt(const short* __restrict__ A,
                                               const short* __restrict__ B,
                                               CT* __restrict__ C,
                                               int M, int N, int K) {
  __shared__ short As[128][72];
  __shared__ short Bs[128][72];

  const int tid  = threadIdx.x;
  const int lane = tid & 63;
  const int w    = tid >> 6;
  const int l16  = lane & 15, g = lane >> 4;
  const int wr   = w >> 1, wc = w & 1;
  const long m0  = (long)blockIdx.y * 128;
  const long n0  = (long)blockIdx.x * 128;

  const f32x4 zero4 = {0.f, 0.f, 0.f, 0.f};
  f32x4 acc[4][4];
  #pragma unroll
  for (int a = 0; a < 4; a++)
    #pragma unroll
    for (int b2 = 0; b2 < 4; b2++) acc[a][b2] = zero4;

  const int srow0 = tid >> 3;
  const int scol  = (tid & 7) * 8;

  const int ktiles = K >> 6;
  for (int kt = 0; kt < ktiles; kt++) {
    const int k0 = kt << 6;
    __syncthreads();
    #pragma unroll
    for (int j = 0; j < 4; j++) {
      const int row = j * 32 + srow0;
      *reinterpret_cast<bf16x8*>(&As[row][scol]) =
          *reinterpret_cast<const bf16x8*>(A + (m0 + row) * K + k0 + scol);
      *reinterpret_cast<bf16x8*>(&Bs[row][scol]) =
          *reinterpret_cast<const bf16x8*>(B + (n0 + row) * K + k0 + scol);
    }
    __syncthreads();
    #pragma unroll
    for (int kk = 0; kk < 2; kk++) {
      bf16x8 af[4], bfr[4];
      #pragma unroll
      for (int f = 0; f < 4; f++)
        af[f] = *reinterpret_cast<const bf16x8*>(&As[wr * 64 + f * 16 + l16][kk * 32 + g * 8]);
      #pragma unroll
      for (int f = 0; f < 4; f++)
        bfr[f] = *reinterpret_cast<const bf16x8*>(&Bs[wc * 64 + f * 16 + l16][kk * 32 + g * 8]);
      #pragma unroll
      for (int fm = 0; fm < 4; fm++)
        #pragma unroll
        for (int fn = 0; fn < 4; fn++)
          acc[fm][fn] = __builtin_amdgcn_mfma_f32_16x16x32_bf16(af[fm], bfr[fn], acc[fm][fn], 0, 0, 0);
    }
  }

  #pragma unroll
  for (int fm = 0; fm < 4; fm++)
    #pragma unroll
    for (int fn = 0; fn < 4; fn++) {
      const long row0 = m0 + wr * 64 + fm * 16 + g * 4;
      const long col  = n0 + wc * 64 + fn * 16 + l16;
      if constexpr (TV) {
        const long base = (((row0 >> 11) * 16 + (col >> 7)) * 128 + (col & 127)) * 2048 + (row0 & 2047);
        short4v pk;
        #pragma unroll
        for (int i = 0; i < 4; i++) pk[i] = f2bf(acc[fm][fn][i]);
        *reinterpret_cast<short4v*>(C + base) = pk;
      } else {
        #pragma unroll
        for (int i = 0; i < 4; i++) {
          const float v = acc[fm][fn][i];
          if constexpr (sizeof(CT) == 2) C[(row0 + i) * N + col] = (CT)f2bf(v);
          else                           C[(row0 + i) * N + col] = v;
        }
      }
    }
}

// ---------------- flash attention v5 ----------------
// Q pre-scaled by QSC in the QKV GEMM. Softmax fast path: per-lane slack check
// (3 in-lane fmax, no cross-lane) + __any vote; the 16-bpermute per-row reduce +
// rescale runs ONLY when the defer threshold fires (always for low heads, ~never
// for heads >= 6 after tile 0).
__global__ __launch_bounds__(256, 3) void attn_kernel(const short* __restrict__ Q,
                                                      const short* __restrict__ K,
                                                      const short* __restrict__ Vt,
                                                      short* __restrict__ Z) {
  __shared__ short Ks[64][136];
  __shared__ short Vs[128][72];
  __shared__ short plds[4][16][72];

  const int tid  = threadIdx.x;
  const int lane = tid & 63;
  const int w    = tid >> 6;
  const int l16  = lane & 15, g = lane >> 4;

  const int bh = blockIdx.x;
  const int bx = 31 - (int)blockIdx.y;    // heavy blocks dispatch first (LPT)
  const int b  = bh >> 4, h = bh & 15;
  const int q0 = bx * 64;

  const float LOG2E  = 1.4426950408889634f;
  const float slope2 = exp2f(-0.5f * (float)(h + 1)) * LOG2E;
  const float CLAMP2 = 1477.3197f;   // 1024*log2e (scores already in exp2 domain)

  bf16x8 qf[4];
  {
    const long qoff = ((long)(b * 2048 + q0 + w * 16 + l16)) * 2048 + h * 128;
    #pragma unroll
    for (int c = 0; c < 4; c++)
      qf[c] = *reinterpret_cast<const bf16x8*>(Q + qoff + c * 32 + g * 8);
  }

  const f32x4 zero4 = {0.f, 0.f, 0.f, 0.f};
  f32x4 zacc[8];
  #pragma unroll
  for (int s = 0; s < 8; s++) zacc[s] = zero4;
  float m2[4], li[4];
  #pragma unroll
  for (int i = 0; i < 4; i++) { m2[i] = -3e38f; li[i] = 0.f; }

  float aj[4];
  #pragma unroll
  for (int ni = 0; ni < 4; ni++) aj[ni] = slope2 * (float)(ni * 16 + l16);

  const int krow = tid >> 4, kcol = (tid & 15) * 8;
  const int vrow = tid >> 3, vcol = (tid & 7) * 8;
  const short* Kh = K + ((long)b * 2048) * 2048 + h * 128;
  const short* Vh = Vt + ((long)(b * 16 + h) * 128) * 2048;

  bf16x8 kreg[4], vreg[4];
  #pragma unroll
  for (int j = 0; j < 4; j++)
    kreg[j] = *reinterpret_cast<const bf16x8*>(Kh + (long)(j * 16 + krow) * 2048 + kcol);
  #pragma unroll
  for (int j = 0; j < 4; j++)
    vreg[j] = *reinterpret_cast<const bf16x8*>(Vh + (long)(j * 32 + vrow) * 2048 + vcol);

  const int ntiles = bx + 1;
  for (int t = 0; t < ntiles; t++) {
    const int kv0 = t * 64;
    __syncthreads();
    #pragma unroll
    for (int j = 0; j < 4; j++)
      *reinterpret_cast<bf16x8*>(&Ks[j * 16 + krow][kcol]) = kreg[j];
    #pragma unroll
    for (int j = 0; j < 4; j++)
      *reinterpret_cast<bf16x8*>(&Vs[j * 32 + vrow][vcol]) = vreg[j];
    __syncthreads();

    f32x4 sc[4];
    #pragma unroll
    for (int ni = 0; ni < 4; ni++) sc[ni] = zero4;
    #pragma unroll
    for (int ni = 0; ni < 4; ni++)
      #pragma unroll
      for (int kc = 0; kc < 4; kc++) {
        const bf16x8 kf = *reinterpret_cast<const bf16x8*>(&Ks[ni * 16 + l16][kc * 32 + g * 8]);
        sc[ni] = __builtin_amdgcn_mfma_f32_16x16x32_bf16(qf[kc], kf, sc[ni], 0, 0, 0);
      }

    if (t + 1 < ntiles) {
      const short* kb = Kh + (long)(kv0 + 64) * 2048;
      const short* vb = Vh + kv0 + 64;
      #pragma unroll
      for (int j = 0; j < 4; j++)
        kreg[j] = *reinterpret_cast<const bf16x8*>(kb + (long)(j * 16 + krow) * 2048 + kcol);
      #pragma unroll
      for (int j = 0; j < 4; j++)
        vreg[j] = *reinterpret_cast<const bf16x8*>(vb + (long)(j * 32 + vrow) * 2048 + vcol);
    }

    // clamp / +alibi / mask; per-lane row max (no cross-lane)
    const float bk = slope2 * (float)kv0;
    float bn[4];
    #pragma unroll
    for (int ni = 0; ni < 4; ni++) bn[ni] = bk + aj[ni];
    float rmax[4];
    float slack = -3e38f;
    #pragma unroll
    for (int i = 0; i < 4; i++) {
      const int qi = q0 + w * 16 + g * 4 + i;
      float mx = -3e38f;
      #pragma unroll
      for (int ni = 0; ni < 4; ni++) {
        const int j = kv0 + ni * 16 + l16;
        float v = fminf(fmaxf(sc[ni][i], -CLAMP2), CLAMP2) + bn[ni];
        v = (j <= qi) ? v : -3e38f;
        sc[ni][i] = v;
        mx = fmaxf(mx, v);
      }
      rmax[i] = mx;
      slack = fmaxf(slack, mx - m2[i]);
    }
    // slow path only when some row's max grew past the defer threshold
    if (__any(slack > 10.f)) {
      #pragma unroll
      for (int i = 0; i < 4; i++) {
        float bb = rmax[i];
        #pragma unroll
        for (int ms = 1; ms < 16; ms <<= 1) bb = fmaxf(bb, __shfl_xor(bb, ms));
        const float mnew = fmaxf(m2[i], bb);
        const float corr = fexp2(m2[i] - mnew);
        m2[i] = mnew;
        li[i] *= corr;
        #pragma unroll
        for (int s = 0; s < 8; s++) zacc[s][i] *= corr;
      }
    }
    // exp2, lane-partial li, P -> plds
    #pragma unroll
    for (int i = 0; i < 4; i++) {
      float psum = 0.f;
      #pragma unroll
      for (int ni = 0; ni < 4; ni++) {
        const float p = fexp2(sc[ni][i] - m2[i]);
        plds[w][g * 4 + i][ni * 16 + l16] = f2bf(p);
        psum += p;
      }
      li[i] += psum;
    }

    bf16x8 paf[2];
    #pragma unroll
    for (int kk = 0; kk < 2; kk++)
      paf[kk] = *reinterpret_cast<const bf16x8*>(&plds[w][l16][kk * 32 + g * 8]);
    #pragma unroll
    for (int s = 0; s < 8; s++) {
      const bf16x8 vf0 = *reinterpret_cast<const bf16x8*>(&Vs[s * 16 + l16][g * 8]);
      const bf16x8 vf1 = *reinterpret_cast<const bf16x8*>(&Vs[s * 16 + l16][32 + g * 8]);
      zacc[s] = __builtin_amdgcn_mfma_f32_16x16x32_bf16(paf[0], vf0, zacc[s], 0, 0, 0);
      zacc[s] = __builtin_amdgcn_mfma_f32_16x16x32_bf16(paf[1], vf1, zacc[s], 0, 0, 0);
    }
  }

  #pragma unroll
  for (int i = 0; i < 4; i++) {
    float s = li[i];
    #pragma unroll
    for (int ms = 1; ms < 16; ms <<= 1) s += __shfl_xor(s, ms);
    li[i] = s;
  }
  #pragma unroll
  for (int s = 0; s < 8; s++)
    #pragma unroll
    for (int i = 0; i < 4; i++) {
      const int qi = q0 + w * 16 + g * 4 + i;
      const float zv = zacc[s][i] / li[i];
      Z[((long)(b * 2048 + qi)) * 2048 + h * 128 + s * 16 + l16] = f2bf(zv);
    }
}

// ---------------- launch ----------------
extern "C" void kernel_launch(void* const* d_in, const int* in_sizes, int n_in,
                              void* d_out, int out_size, void* d_ws, size_t ws_size,
                              hipStream_t stream) {
  const float* X  = (const float*)d_in[0];
  const float* Wq = (const float*)d_in[1];
  const float* Wk = (const float*)d_in[2];
  const float* Wv = (const float*)d_in[3];
  const float* Wo = (const float*)d_in[4];
  float* out = (float*)d_out;

  short* ws    = (short*)d_ws;
  short* Xb    = ws;                     // 8,388,608
  short* Wqkvb = ws + 8388608;           // 12,582,912 (Wq|Wk|Wv rows)
  short* Wob   = ws + 20971520;          // 4,194,304
  short* Qb    = ws + 25165824;          // 8,388,608
  short* Kb    = ws + 33554432;          // 8,388,608
  short* Vtb   = ws + 41943040;          // 8,388,608
  short* Zb    = Xb;

  cast_kernel<<<8192, 256, 0, stream>>>(X, Xb, 2097152);
  dim3 gw(4096, 4);
  cast_w_kernel<<<gw, 256, 0, stream>>>(Wq, Wk, Wv, Wo, Wqkvb, Wob);

  gemm_qkv8<<<512, 512, 0, stream>>>(Xb, Wqkvb, Qb, Kb, Vtb);

  dim3 ga(32, 32);
  attn_kernel<<<ga, 256, 0, stream>>>(Qb, Kb, Vtb, Zb);

  dim3 gg(16, 32);
  gemm_bt<float, false><<<gg, 256, 0, stream>>>(Zb, Wob, out, 4096, 2048, 2048);
}